// Round 10
// baseline (241.186 us; speedup 1.0000x reference)
//
#include <hip/hip_runtime.h>
#include <hip/hip_bf16.h>
#include <stdint.h>

#define DM 768
#define SQ 4096
#define NH 12

typedef __bf16 bf16;
typedef __bf16 bf16x8 __attribute__((ext_vector_type(8)));
typedef float floatx4 __attribute__((ext_vector_type(4)));
typedef short short4v __attribute__((ext_vector_type(4)));

#if defined(__has_builtin)
#if __has_builtin(__builtin_amdgcn_mfma_f32_16x16x16bf16_1k)
#define HAVE_MFMA16 1
#endif
#endif
#ifndef HAVE_MFMA16
#define HAVE_MFMA16 0
#endif

typedef __attribute__((address_space(1))) const uint32_t cu32_g;
typedef __attribute__((address_space(3))) uint32_t u32_l;

__device__ __forceinline__ uint16_t f2bf(float f) {
  uint32_t u = __builtin_bit_cast(uint32_t, f);
  u += 0x7fff + ((u >> 16) & 1);
  return (uint16_t)(u >> 16);
}

__device__ __forceinline__ uint32_t pk2(float lo, float hi) {
  __hip_bfloat162 h = __float22bfloat162_rn(float2{lo, hi});
  uint32_t u;
  __builtin_memcpy(&u, &h, 4);
  return u;
}

__device__ __forceinline__ float bflo(uint32_t u) {
  return __builtin_bit_cast(float, u << 16);
}
__device__ __forceinline__ float bfhi(uint32_t u) {
  return __builtin_bit_cast(float, u & 0xffff0000u);
}

// async global->LDS, 16B/lane; LDS dst is wave-uniform base, lane i -> base+i*16
__device__ __forceinline__ void async16(const bf16* g, bf16* l) {
  __builtin_amdgcn_global_load_lds((cu32_g*)g, (u32_l*)l, 16, 0, 0);
}

// ---- persistent-block schedule ---------------------------------------------
// 160 (qb,c) units per head (qb 0..63, chunks of 1024 kv), heavy-first.
// Global unit g in [0,1920): i = g/12 (unit), h = g%12 (head). 1280 blocks
// (5/CU, all co-resident); block b covers units with prefix-cost in
// [b*C/1280, (b+1)*C/1280), C = 24960 total kv-iterations. Max unit cost 16
// < quota 19.5, so per-block imbalance is bounded and the block-granular
// second-wave tail (R4..R9: avg occupancy half of capacity) is eliminated.
struct SchedT { uint16_t unit[160]; uint16_t start[1281]; };
static constexpr SchedT make_sched() {
  SchedT s{};
  int cost[160] = {};
  int idx = 0;
  for (int nit = 16; nit >= 1; --nit)
    for (int qb = 63; qb >= 0; --qb) {
      int len = (qb + 1) * 64;
      int nch = (len + 1023) >> 10;
      for (int c = nch - 1; c >= 0; --c) {
        int cs = c * 1024;
        int ce = (len < cs + 1024) ? len : cs + 1024;
        int ni = (ce - cs) >> 6;
        if (ni == nit) { s.unit[idx] = (uint16_t)(qb * 4 + c); cost[idx] = ni; ++idx; }
      }
    }
  long total = 0;
  for (int i = 0; i < 160; ++i) total += cost[i];
  total *= 12;                       // 24960
  long acc = 0;
  int b = 0;
  s.start[0] = 0;
  for (int g = 0; g < 1920; ++g) {
    acc += cost[g / 12];
    while (b + 1 < 1280 && acc * 1280 >= (long)(b + 1) * total) {
      ++b;
      s.start[b] = (uint16_t)(g + 1);
    }
  }
  for (int bb = b + 1; bb <= 1280; ++bb) s.start[bb] = 1920;
  return s;
}
__device__ __constant__ SchedT kSched = make_sched();

// ---------------- convert fp32 -> bf16 ----------------
__global__ __launch_bounds__(256) void cvt_kernel(
    const float* __restrict__ x, const float* __restrict__ wq,
    const float* __restrict__ wk, const float* __restrict__ wv,
    const float* __restrict__ wp, bf16* __restrict__ xb, bf16* __restrict__ wqb,
    bf16* __restrict__ wkb, bf16* __restrict__ wvb, bf16* __restrict__ wpb) {
  const int XQ = (SQ * DM) / 4;
  const int WQ = (DM * DM) / 4;
  int t = blockIdx.x * 256 + threadIdx.x;
  const float* src;
  bf16* dst;
  int local;
  if (t < XQ) { src = x;  dst = xb;  local = t; }
  else if (t < XQ + WQ)     { src = wq; dst = wqb; local = t - XQ; }
  else if (t < XQ + 2 * WQ) { src = wk; dst = wkb; local = t - XQ - WQ; }
  else if (t < XQ + 3 * WQ) { src = wv; dst = wvb; local = t - XQ - 2 * WQ; }
  else                      { src = wp; dst = wpb; local = t - XQ - 3 * WQ; }
  float4 v = ((const float4*)src)[local];
  ushort4 o;
  o.x = f2bf(v.x); o.y = f2bf(v.y); o.z = f2bf(v.z); o.w = f2bf(v.w);
  ((ushort4*)dst)[local] = o;
}

// ---------------- NT GEMM core 128x128, double-buffered staging -----------
__device__ __forceinline__ void gemm_core(const bf16* __restrict__ A,
                                          const bf16* __restrict__ B, int m0,
                                          int n0, floatx4 (&acc)[4][4]) {
  __shared__ bf16 lA[2 * 4096];
  __shared__ bf16 lB[2 * 4096];
  const int tid = threadIdx.x;
  const int lane = tid & 63;
  const int w = tid >> 6;

  const int r0 = w * 32 + (lane >> 2);
  const int ke = (((lane & 3) ^ ((lane >> 3) & 3))) * 8;  // swizzled src chunk
  const bf16* gA0 = A + (size_t)(m0 + r0) * DM + ke;
  const bf16* gA1 = A + (size_t)(m0 + r0 + 16) * DM + ke;
  const bf16* gB0 = B + (size_t)(n0 + r0) * DM + ke;
  const bf16* gB1 = B + (size_t)(n0 + r0 + 16) * DM + ke;

  async16(gA0, lA + w * 1024); async16(gA1, lA + w * 1024 + 512);
  async16(gB0, lB + w * 1024); async16(gB1, lB + w * 1024 + 512);
  gA0 += 32; gA1 += 32; gB0 += 32; gB1 += 32;

  const int mrow = (w >> 1) * 64 + (lane & 15);
  const int nrow = (w & 1) * 64 + (lane & 15);
  const int cswz = ((lane >> 4) ^ ((lane >> 1) & 3)) * 8;  // swizzled read chunk

  for (int kt = 0; kt < DM / 32; ++kt) {
    __syncthreads();  // drains loads issued last iter (full iter of cover)
    if (kt + 1 < DM / 32) {
      const int nb = ((kt + 1) & 1) * 4096;
      async16(gA0, lA + nb + w * 1024); async16(gA1, lA + nb + w * 1024 + 512);
      async16(gB0, lB + nb + w * 1024); async16(gB1, lB + nb + w * 1024 + 512);
      gA0 += 32; gA1 += 32; gB0 += 32; gB1 += 32;
    }
    const int cb = (kt & 1) * 4096;
    bf16x8 a[4], b[4];
#pragma unroll
    for (int mt = 0; mt < 4; ++mt)
      a[mt] = *(const bf16x8*)&lA[cb + (mrow + mt * 16) * 32 + cswz];
#pragma unroll
    for (int nt = 0; nt < 4; ++nt)
      b[nt] = *(const bf16x8*)&lB[cb + (nrow + nt * 16) * 32 + cswz];
#pragma unroll
    for (int mt = 0; mt < 4; ++mt)
#pragma unroll
      for (int nt = 0; nt < 4; ++nt)
        acc[mt][nt] = __builtin_amdgcn_mfma_f32_16x16x32_bf16(
            a[mt], b[nt], acc[mt][nt], 0, 0, 0);
  }
}

// QKV: z=0 -> Q (pre-scaled by 0.125*log2e); z=1 -> K; z=2 -> V^T
__global__ __launch_bounds__(256) void qkv_kernel(
    const bf16* __restrict__ xb, const bf16* __restrict__ wq,
    const bf16* __restrict__ wk, const bf16* __restrict__ wv,
    bf16* __restrict__ Qb, bf16* __restrict__ Kb, bf16* __restrict__ Vtb) {
  const int z = blockIdx.z;
  const bf16* B = (z == 0) ? wq : (z == 1) ? wk : wv;
  const int m0 = blockIdx.x * 128, n0 = blockIdx.y * 128;
  floatx4 acc[4][4] = {};
  gemm_core(xb, B, m0, n0, acc);
  const int lane = threadIdx.x & 63, w = threadIdx.x >> 6;
  const int quad = lane >> 4, ql = lane & 15;
  const float qs = (z == 0) ? 0.18033688011112042f : 1.0f;  // 0.125*log2(e)
  if (z < 2) {
    bf16* C = (z == 0) ? Qb : Kb;
#pragma unroll
    for (int mt = 0; mt < 4; ++mt)
#pragma unroll
      for (int nt = 0; nt < 4; ++nt) {
        int row = m0 + (w >> 1) * 64 + mt * 16 + quad * 4;
        int col = n0 + (w & 1) * 64 + nt * 16 + ql;
#pragma unroll
        for (int r = 0; r < 4; ++r)
          *(uint16_t*)&C[(size_t)(row + r) * DM + col] = f2bf(acc[mt][nt][r] * qs);
      }
  } else {
#pragma unroll
    for (int mt = 0; mt < 4; ++mt)
#pragma unroll
      for (int nt = 0; nt < 4; ++nt) {
        int row = m0 + (w >> 1) * 64 + mt * 16 + quad * 4;  // s
        int col = n0 + (w & 1) * 64 + nt * 16 + ql;         // d
        uint32_t lo = pk2(acc[mt][nt][0], acc[mt][nt][1]);
        uint32_t hi = pk2(acc[mt][nt][2], acc[mt][nt][3]);
        *(uint2*)&Vtb[(size_t)col * SQ + row] = make_uint2(lo, hi);
      }
  }
}

// output projection, 64x128 tiles (384 blocks), double-buffered staging
__global__ __launch_bounds__(256) void proj_kernel(
    const bf16* __restrict__ Ob, const bf16* __restrict__ wp,
    float* __restrict__ out) {
  __shared__ bf16 lA[2 * 2048];
  __shared__ bf16 lB[2 * 4096];
  const int tid = threadIdx.x, lane = tid & 63, w = tid >> 6;
  const int m0 = blockIdx.x * 64, n0 = blockIdx.y * 128;

  const int ke = (((lane & 3) ^ ((lane >> 3) & 3))) * 8;
  const bf16* gA = Ob + (size_t)(m0 + w * 16 + (lane >> 2)) * DM + ke;
  const bf16* gB0 = wp + (size_t)(n0 + w * 32 + (lane >> 2)) * DM + ke;
  const bf16* gB1 = wp + (size_t)(n0 + w * 32 + (lane >> 2) + 16) * DM + ke;

  async16(gA, lA + w * 512);
  async16(gB0, lB + w * 1024); async16(gB1, lB + w * 1024 + 512);
  gA += 32; gB0 += 32; gB1 += 32;

  const int mrow = (w >> 1) * 32 + (lane & 15);
  const int nrow = (w & 1) * 64 + (lane & 15);
  const int cswz = ((lane >> 4) ^ ((lane >> 1) & 3)) * 8;
  floatx4 acc[2][4] = {};

  for (int kt = 0; kt < DM / 32; ++kt) {
    __syncthreads();
    if (kt + 1 < DM / 32) {
      const int nbA = ((kt + 1) & 1) * 2048, nbB = ((kt + 1) & 1) * 4096;
      async16(gA, lA + nbA + w * 512);
      async16(gB0, lB + nbB + w * 1024); async16(gB1, lB + nbB + w * 1024 + 512);
      gA += 32; gB0 += 32; gB1 += 32;
    }
    const int cbA = (kt & 1) * 2048, cbB = (kt & 1) * 4096;
    bf16x8 a[2], b[4];
#pragma unroll
    for (int mt = 0; mt < 2; ++mt)
      a[mt] = *(const bf16x8*)&lA[cbA + (mrow + mt * 16) * 32 + cswz];
#pragma unroll
    for (int nt = 0; nt < 4; ++nt)
      b[nt] = *(const bf16x8*)&lB[cbB + (nrow + nt * 16) * 32 + cswz];
#pragma unroll
    for (int mt = 0; mt < 2; ++mt)
#pragma unroll
      for (int nt = 0; nt < 4; ++nt)
        acc[mt][nt] = __builtin_amdgcn_mfma_f32_16x16x32_bf16(
            a[mt], b[nt], acc[mt][nt], 0, 0, 0);
  }
  const int quad = lane >> 4, ql = lane & 15;
#pragma unroll
  for (int mt = 0; mt < 2; ++mt)
#pragma unroll
    for (int nt = 0; nt < 4; ++nt) {
      int row = m0 + (w >> 1) * 32 + mt * 16 + quad * 4;
      int col = n0 + (w & 1) * 64 + nt * 16 + ql;
#pragma unroll
      for (int r = 0; r < 4; ++r)
        out[(size_t)(row + r) * DM + col] = acc[mt][nt][r];
    }
}

// ---------------- split-KV causal flash attention (transposed) ------------
// PERSISTENT BLOCKS: 1280 blocks (5/CU, fully co-resident); each processes
// a prefix-balanced range of (unit, head) work items. Inner body identical
// to the proven R7 kernel (64q x 64kv tile, 4 waves = 2 qh x 2 kh, 32 KB
// dbuf K/V, fixed-base softmax, scalar l sums). One extra __syncthreads()
// per unit guards LDS reuse across units.
__global__ __launch_bounds__(256, 5) void attn_kernel(
    const bf16* __restrict__ Qb, const bf16* __restrict__ Kb,
    const bf16* __restrict__ Vtb, uint16_t* __restrict__ OpartB,
    float* __restrict__ Lpart, bf16* __restrict__ Ob) {
#if HAVE_MFMA16
  __shared__ __align__(16) char smem[32768];
#else
  __shared__ __align__(16) char smem[40960];
  bf16* lPt = (bf16*)(smem + 32768);  // 8 KB P^T scratch, 2 KB per wave
#endif
  // buffer b (b=0,1) at smem + b*16384: K = 8 KB (2 dchunks [64][32]),
  // V = 8 KB at +8192 (2 kv-chunks [64 d][32 kv]); both source-swizzled.
  const int tid = threadIdx.x, lane = tid & 63, w = tid >> 6;  // w: 0..3
  const int quad = lane >> 4, ql = lane & 15;
  const int qh = w & 1;   // q half  (32 rows)
  const int kh = w >> 1;  // kv half (32 cols)
  const int src_e = (((lane & 3) ^ ((lane >> 3) & 3))) * 8;
  const int cswz = ((lane >> 4) ^ ((lane >> 1) & 3)) * 8;

  const int g0 = kSched.start[blockIdx.x];
  const int g1 = kSched.start[blockIdx.x + 1];

  for (int g = g0; g < g1; ++g) {
    const int i = g / 12;
    const int h = g - i * 12;
    const int e = kSched.unit[i];
    const int qb = e >> 2, c = e & 3;
    const int kv0 = c * 1024;
    const int qlen = (qb + 1) * 64;
    const int kv_end = min(qlen, kv0 + 1024);
    const int n_it = (kv_end - kv0) >> 6;  // 1..16
    const bool diag = (kv_end == qlen);

    // Q fragments (pre-scaled), B-operand layout; 32 q rows per wave
    bf16x8 qf[2][2];
#pragma unroll
    for (int nt = 0; nt < 2; ++nt)
#pragma unroll
      for (int kt = 0; kt < 2; ++kt)
        qf[nt][kt] = *(const bf16x8*)&Qb[(size_t)(qb * 64 + qh * 32 + nt * 16 + ql) * DM +
                                         h * 64 + kt * 32 + quad * 8];

    // staging pointers (source-side XOR chunk swizzle); 2 K + 2 V per thread
    const bf16* gK[2];
    const bf16* gV[2];
#pragma unroll
    for (int t = 0; t < 2; ++t) {
      int o = t * 4096 + w * 1024 + lane * 16;  // byte in 8KB K image
      int cK = o >> 12, rK = (o & 4095) >> 6;
      gK[t] = Kb + (size_t)(kv0 + rK) * DM + h * 64 + cK * 32 + src_e;
      int dV = w * 16 + (lane >> 2);            // V image: [t][dV][32]
      gV[t] = Vtb + (size_t)(h * 64 + dV) * SQ + kv0 + t * 32 + src_e;
    }

    __syncthreads();  // prev unit's epilogue LDS reads done before restaging
    // prologue: stage K(0)+V(0) into buf 0
#pragma unroll
    for (int t = 0; t < 2; ++t) {
      async16(gK[t], (bf16*)(smem + t * 4096 + w * 1024));
      async16(gV[t], (bf16*)(smem + 8192 + t * 4096 + w * 1024));
      gK[t] += 64 * DM;
      gV[t] += 64;
    }

    floatx4 o_acc[4][2] = {};
    float l_s[2] = {0.f, 0.f};

    for (int j = 0; j < n_it; ++j) {
      __syncthreads();  // drains (j) tiles staged last iter
      if (j + 1 < n_it) {
        char* dst = smem + ((j + 1) & 1) * 16384;
#pragma unroll
        for (int t = 0; t < 2; ++t) {
          async16(gK[t], (bf16*)(dst + t * 4096 + w * 1024));
          async16(gV[t], (bf16*)(dst + 8192 + t * 4096 + w * 1024));
          gK[t] += 64 * DM;
          gV[t] += 64;
        }
      }
      const char* cbuf = smem + (j & 1) * 16384;
      const bf16* kbuf = (const bf16*)cbuf;
      const char* vbuf = cbuf + 8192;

      // QK^T: S[32 kv (kh half)][32 q (qh half)]
      floatx4 s[2][2] = {};
      __builtin_amdgcn_s_setprio(1);
#pragma unroll
      for (int kt = 0; kt < 2; ++kt)
#pragma unroll
        for (int mt = 0; mt < 2; ++mt) {
          bf16x8 a = *(const bf16x8*)&kbuf[kt * 2048 + (kh * 32 + mt * 16 + ql) * 32 + cswz];
#pragma unroll
          for (int nt = 0; nt < 2; ++nt)
            s[mt][nt] = __builtin_amdgcn_mfma_f32_16x16x32_bf16(a, qf[nt][kt],
                                                                s[mt][nt], 0, 0, 0);
        }
      __builtin_amdgcn_s_setprio(0);

      // diagonal lives entirely in the last 64-kv iteration (q tile = 64)
      if (diag && j == n_it - 1) {
#pragma unroll
        for (int mt = 0; mt < 2; ++mt)
#pragma unroll
          for (int nt = 0; nt < 2; ++nt) {
            const int qpos = qh * 32 + nt * 16 + ql;
#pragma unroll
            for (int r = 0; r < 4; ++r) {
              int kpos = kh * 32 + mt * 16 + quad * 4 + r;
              if (kpos > qpos) s[mt][nt][r] = -1e30f;
            }
          }
      }

      // fixed-base softmax: exp2 + pack + tree-sum, one pass
      uint2 pp[2][2];
#pragma unroll
      for (int nt = 0; nt < 2; ++nt) {
        float tsum[2];
#pragma unroll
        for (int mt = 0; mt < 2; ++mt) {
          float p0 = __builtin_amdgcn_exp2f(s[mt][nt][0]);
          float p1 = __builtin_amdgcn_exp2f(s[mt][nt][1]);
          float p2 = __builtin_amdgcn_exp2f(s[mt][nt][2]);
          float p3 = __builtin_amdgcn_exp2f(s[mt][nt][3]);
          pp[mt][nt] = make_uint2(pk2(p0, p1), pk2(p2, p3));
          tsum[mt] = (p0 + p1) + (p2 + p3);
        }
        l_s[nt] += tsum[0] + tsum[1];
      }

#if HAVE_MFMA16
      // PV: O^T[d][q] += V^T(kh half) · P^T, B-frags from packed regs
      __builtin_amdgcn_s_setprio(1);
#pragma unroll
      for (int mt = 0; mt < 2; ++mt) {
        short4v bfr[2];
#pragma unroll
        for (int nt = 0; nt < 2; ++nt) {
          union { uint2 u; short4v v; } pb;
          pb.u = pp[mt][nt];
          bfr[nt] = pb.v;
        }
        const char* vbase = vbuf + kh * 4096 +
            (((mt * 2 + (quad >> 1)) ^ ((ql >> 1) & 3)) * 16) +
            (quad & 1) * 8;
#pragma unroll
        for (int mtd = 0; mtd < 4; ++mtd) {
          short4v a = *(const short4v*)(vbase + (mtd * 16 + ql) * 64);
#pragma unroll
          for (int nt = 0; nt < 2; ++nt)
            o_acc[mtd][nt] = __builtin_amdgcn_mfma_f32_16x16x16bf16_1k(
                a, bfr[nt], o_acc[mtd][nt], 0, 0, 0);
        }
      }
      __builtin_amdgcn_s_setprio(0);
#else
      // PV via wave-private LDS P^T transpose (one 32-kv group per wave)
      bf16* lp = lPt + w * 1024;  // 2 KB per wave (32 q rows x 64 B)
      {
#pragma unroll
        for (int nt = 0; nt < 2; ++nt) {
          int q32 = nt * 16 + ql;
          int key = (q32 >> 1) & 7;
#pragma unroll
          for (int mtp = 0; mtp < 2; ++mtp) {
            int slot = mtp * 4 + quad;
            *(uint2*)((char*)lp + q32 * 64 + ((slot ^ key) * 8)) = pp[mtp][nt];
          }
        }
        bf16x8 bp[2];
#pragma unroll
        for (int nt = 0; nt < 2; ++nt) {
          int q32 = nt * 16 + ql;
          int key = (q32 >> 1) & 7;
          union { uint2 u[2]; bf16x8 v; } pb;
          pb.u[0] = *(uint2*)((char*)lp + q32 * 64 + (((2 * quad) ^ key) * 8));
          pb.u[1] = *(uint2*)((char*)lp + q32 * 64 + (((2 * quad + 1) ^ key) * 8));
          bp[nt] = pb.v;
        }
#pragma unroll
        for (int mtd = 0; mtd < 4; ++mtd) {
          bf16x8 a = *(const bf16x8*)((const bf16*)vbuf + kh * 2048 +
                                      (mtd * 16 + ql) * 32 + cswz);
#pragma unroll
          for (int nt = 0; nt < 2; ++nt)
            o_acc[mtd][nt] = __builtin_amdgcn_mfma_f32_16x16x32_bf16(
                a, bp[nt], o_acc[mtd][nt], 0, 0, 0);
        }
      }
#endif
    }

    // ---- cross-wave kv-half reduction through the free LDS buffer --------
    char* fb = smem + ((n_it & 1) * 16384);        // buffer not computed last
    char* lb = smem + (((n_it - 1) & 1) * 16384);  // last-computed buffer
    __syncthreads();  // all PV reads of last buffer done
    if (kh == 1) {
      char* po = fb + (w - 2) * 8192;
#pragma unroll
      for (int nt = 0; nt < 2; ++nt)
#pragma unroll
        for (int mtd = 0; mtd < 4; ++mtd)
          *(floatx4*)(po + (nt * 4 + mtd) * 1024 + lane * 16) = o_acc[mtd][nt];
      float2* pl = (float2*)(lb + (w - 2) * 512);
      pl[lane] = make_float2(l_s[0], l_s[1]);
    }
    __syncthreads();
    if (kh == 0) {
      char* po = fb + w * 8192;
#pragma unroll
      for (int nt = 0; nt < 2; ++nt)
#pragma unroll
        for (int mtd = 0; mtd < 4; ++mtd)
          o_acc[mtd][nt] += *(const floatx4*)(po + (nt * 4 + mtd) * 1024 + lane * 16);
      float2 l2 = ((const float2*)(lb + w * 512))[lane];
      l_s[0] += l2.x;
      l_s[1] += l2.y;

      // finalize l across the 4 lane-groups
      float lf[2];
#pragma unroll
      for (int nt = 0; nt < 2; ++nt) {
        float ls = l_s[nt];
        ls += __shfl_xor(ls, 16);
        ls += __shfl_xor(ls, 32);
        lf[nt] = ls;
      }

      if (qb < 16) {
        // single-chunk tile: normalized direct store
#pragma unroll
        for (int nt = 0; nt < 2; ++nt) {
          float rl = 1.0f / lf[nt];
          int qg = qb * 64 + qh * 32 + nt * 16 + ql;
#pragma unroll
          for (int mtd = 0; mtd < 4; ++mtd) {
            uint32_t lo = pk2(o_acc[mtd][nt][0] * rl, o_acc[mtd][nt][1] * rl);
            uint32_t hi = pk2(o_acc[mtd][nt][2] * rl, o_acc[mtd][nt][3] * rl);
            *(uint2*)&Ob[(size_t)qg * DM + h * 64 + mtd * 16 + quad * 4] =
                make_uint2(lo, hi);
          }
        }
      } else {
        const int ps = (h * 64 + qb) * 4 + c;
#pragma unroll
        for (int nt = 0; nt < 2; ++nt) {
          int q = qh * 32 + nt * 16 + ql;
          if (quad == 0) Lpart[ps * 64 + q] = lf[nt];
#pragma unroll
          for (int mtd = 0; mtd < 4; ++mtd) {
            uint32_t lo = pk2(o_acc[mtd][nt][0], o_acc[mtd][nt][1]);
            uint32_t hi = pk2(o_acc[mtd][nt][2], o_acc[mtd][nt][3]);
            *(uint2*)&OpartB[(size_t)ps * 4096 + q * 64 + mtd * 16 + quad * 4] =
                make_uint2(lo, hi);
          }
        }
      }
    }
  }
}

// merge <=4 bf16 partials per (h, qb>=16) -> Ob (fixed base: plain sums)
__global__ __launch_bounds__(256) void combine_kernel(
    const uint16_t* __restrict__ OpartB, const float* __restrict__ Lpart,
    bf16* __restrict__ Ob) {
  int b = blockIdx.x;                 // 576 = 48 * 12
  int h = b % NH, qb = 16 + b / NH;
  int nch = (qb + 16) >> 4;           // 2..4
  int t = threadIdx.x;
  int q = t >> 2, dh = (t & 3) * 16;  // 64 q x 4 d-slots of 16
  int ps0 = (h * 64 + qb) * 4;

  float acc[16] = {};
  float L = 0.f;
#pragma unroll
  for (int cc = 0; cc < 4; ++cc)
    if (cc < nch) {
      L += Lpart[(ps0 + cc) * 64 + q];
      const uint4* p =
          (const uint4*)(OpartB + (size_t)(ps0 + cc) * 4096 + q * 64 + dh);
#pragma unroll
      for (int g = 0; g < 2; ++g) {
        uint4 u = p[g];
        acc[g * 8 + 0] += bflo(u.x); acc[g * 8 + 1] += bfhi(u.x);
        acc[g * 8 + 2] += bflo(u.y); acc[g * 8 + 3] += bfhi(u.y);
        acc[g * 8 + 4] += bflo(u.z); acc[g * 8 + 5] += bfhi(u.z);
        acc[g * 8 + 6] += bflo(u.w); acc[g * 8 + 7] += bfhi(u.w);
      }
    }
  float rl = 1.0f / L;
  bf16* dst = &Ob[(size_t)(qb * 64 + q) * DM + h * 64 + dh];
#pragma unroll
  for (int g = 0; g < 2; ++g) {
    uint4 u;
    u.x = pk2(acc[g * 8 + 0] * rl, acc[g * 8 + 1] * rl);
    u.y = pk2(acc[g * 8 + 2] * rl, acc[g * 8 + 3] * rl);
    u.z = pk2(acc[g * 8 + 4] * rl, acc[g * 8 + 5] * rl);
    u.w = pk2(acc[g * 8 + 6] * rl, acc[g * 8 + 7] * rl);
    *(uint4*)&dst[g * 8] = u;
  }
}

extern "C" void kernel_launch(void* const* d_in, const int* in_sizes, int n_in,
                              void* d_out, int out_size, void* d_ws,
                              size_t ws_size, hipStream_t stream) {
  const float* x  = (const float*)d_in[0];
  const float* wq = (const float*)d_in[1];
  const float* wk = (const float*)d_in[2];
  const float* wv = (const float*)d_in[3];
  const float* wp = (const float*)d_in[4];
  char* ws = (char*)d_ws;
  // Lpart lives in the xb region (dead after qkv; attn rewrites before
  // combine reads). Peak ws usage = 61341696 B (unchanged layout).
  float* Lpart = (float*)(ws);             // 3072*64*4 = 786432 (inside xb)
  bf16* xb   = (bf16*)(ws);
  bf16* wqb  = (bf16*)(ws + 6291456);
  bf16* wkb  = (bf16*)(ws + 7471104);
  bf16* wvb  = (bf16*)(ws + 8650752);
  bf16* wpb  = (bf16*)(ws + 9830400);
  bf16* Qb   = (bf16*)(ws + 11010048);
  bf16* Kb   = (bf16*)(ws + 17301504);
  bf16* Vtb  = (bf16*)(ws + 23592960);
  bf16* Ob   = (bf16*)(ws + 29884416);
  uint16_t* OpartB = (uint16_t*)(ws + 36175872);  // 3072 x 4096 bf16 -> 61341696

  cvt_kernel<<<5376, 256, 0, stream>>>(x, wq, wk, wv, wp, xb, wqb, wkb, wvb, wpb);
  qkv_kernel<<<dim3(32, 6, 3), 256, 0, stream>>>(xb, wqb, wkb, wvb, Qb, Kb, Vtb);
  attn_kernel<<<1280, 256, 0, stream>>>(Qb, Kb, Vtb, OpartB, Lpart, Ob);
  combine_kernel<<<576, 256, 0, stream>>>(OpartB, Lpart, Ob);
  proj_kernel<<<dim3(64, 6), 256, 0, stream>>>(Ob, wpb, (float*)d_out);
}

// Round 11
// 163.416 us; speedup vs baseline: 1.4759x; 1.4759x over previous
//
#include <hip/hip_runtime.h>
#include <hip/hip_bf16.h>
#include <stdint.h>

#define DM 768
#define SQ 4096
#define NH 12

typedef __bf16 bf16;
typedef __bf16 bf16x8 __attribute__((ext_vector_type(8)));
typedef float floatx4 __attribute__((ext_vector_type(4)));
typedef short short4v __attribute__((ext_vector_type(4)));

#if defined(__has_builtin)
#if __has_builtin(__builtin_amdgcn_mfma_f32_16x16x16bf16_1k)
#define HAVE_MFMA16 1
#endif
#endif
#ifndef HAVE_MFMA16
#define HAVE_MFMA16 0
#endif

typedef __attribute__((address_space(1))) const uint32_t cu32_g;
typedef __attribute__((address_space(3))) uint32_t u32_l;

__device__ __forceinline__ uint16_t f2bf(float f) {
  uint32_t u = __builtin_bit_cast(uint32_t, f);
  u += 0x7fff + ((u >> 16) & 1);
  return (uint16_t)(u >> 16);
}

__device__ __forceinline__ uint32_t pk2(float lo, float hi) {
  __hip_bfloat162 h = __float22bfloat162_rn(float2{lo, hi});
  uint32_t u;
  __builtin_memcpy(&u, &h, 4);
  return u;
}

__device__ __forceinline__ float bflo(uint32_t u) {
  return __builtin_bit_cast(float, u << 16);
}
__device__ __forceinline__ float bfhi(uint32_t u) {
  return __builtin_bit_cast(float, u & 0xffff0000u);
}

// async global->LDS, 16B/lane; LDS dst is wave-uniform base, lane i -> base+i*16
__device__ __forceinline__ void async16(const bf16* g, bf16* l) {
  __builtin_amdgcn_global_load_lds((cu32_g*)g, (u32_l*)l, 16, 0, 0);
}

// ---- heavy-first (qb, c) schedule for 64-q tiles, 1024-kv chunks ----------
// 160 units per head: qb 0..63, chunks c with c*1024 < (qb+1)*64.
// Sorted by n_it (64-kv iterations) descending, then qb descending.
// NOTE (R10 lesson): launch-order clustering of consecutive units gives the
// L2 reuse (units sharing a KV chunk run concurrently); do NOT replace with
// persistent-block partitioning (FETCH 17 -> 131 MB, attn 45.7 -> 123 us).
struct MapT { uint16_t v[160]; };
static constexpr MapT make_map() {
  MapT m{};
  int idx = 0;
  for (int nit = 16; nit >= 1; --nit)
    for (int qb = 63; qb >= 0; --qb) {
      int len = (qb + 1) * 64;
      int nch = (len + 1023) >> 10;
      for (int c = nch - 1; c >= 0; --c) {
        int cs = c * 1024;
        int ce = (len < cs + 1024) ? len : cs + 1024;
        int ni = (ce - cs) >> 6;
        if (ni == nit) m.v[idx++] = (uint16_t)(qb * 4 + c);
      }
    }
  return m;
}
__device__ __constant__ MapT kMap = make_map();

// ---------------- convert fp32 -> bf16 ----------------
__global__ __launch_bounds__(256) void cvt_kernel(
    const float* __restrict__ x, const float* __restrict__ wq,
    const float* __restrict__ wk, const float* __restrict__ wv,
    const float* __restrict__ wp, bf16* __restrict__ xb, bf16* __restrict__ wqb,
    bf16* __restrict__ wkb, bf16* __restrict__ wvb, bf16* __restrict__ wpb) {
  const int XQ = (SQ * DM) / 4;
  const int WQ = (DM * DM) / 4;
  int t = blockIdx.x * 256 + threadIdx.x;
  const float* src;
  bf16* dst;
  int local;
  if (t < XQ) { src = x;  dst = xb;  local = t; }
  else if (t < XQ + WQ)     { src = wq; dst = wqb; local = t - XQ; }
  else if (t < XQ + 2 * WQ) { src = wk; dst = wkb; local = t - XQ - WQ; }
  else if (t < XQ + 3 * WQ) { src = wv; dst = wvb; local = t - XQ - 2 * WQ; }
  else                      { src = wp; dst = wpb; local = t - XQ - 3 * WQ; }
  float4 v = ((const float4*)src)[local];
  ushort4 o;
  o.x = f2bf(v.x); o.y = f2bf(v.y); o.z = f2bf(v.z); o.w = f2bf(v.w);
  ((ushort4*)dst)[local] = o;
}

// ---------------- NT GEMM core 128x128, double-buffered staging -----------
__device__ __forceinline__ void gemm_core(const bf16* __restrict__ A,
                                          const bf16* __restrict__ B, int m0,
                                          int n0, floatx4 (&acc)[4][4]) {
  __shared__ bf16 lA[2 * 4096];
  __shared__ bf16 lB[2 * 4096];
  const int tid = threadIdx.x;
  const int lane = tid & 63;
  const int w = tid >> 6;

  const int r0 = w * 32 + (lane >> 2);
  const int ke = (((lane & 3) ^ ((lane >> 3) & 3))) * 8;  // swizzled src chunk
  const bf16* gA0 = A + (size_t)(m0 + r0) * DM + ke;
  const bf16* gA1 = A + (size_t)(m0 + r0 + 16) * DM + ke;
  const bf16* gB0 = B + (size_t)(n0 + r0) * DM + ke;
  const bf16* gB1 = B + (size_t)(n0 + r0 + 16) * DM + ke;

  async16(gA0, lA + w * 1024); async16(gA1, lA + w * 1024 + 512);
  async16(gB0, lB + w * 1024); async16(gB1, lB + w * 1024 + 512);
  gA0 += 32; gA1 += 32; gB0 += 32; gB1 += 32;

  const int mrow = (w >> 1) * 64 + (lane & 15);
  const int nrow = (w & 1) * 64 + (lane & 15);
  const int cswz = ((lane >> 4) ^ ((lane >> 1) & 3)) * 8;  // swizzled read chunk

  for (int kt = 0; kt < DM / 32; ++kt) {
    __syncthreads();  // drains loads issued last iter (full iter of cover)
    if (kt + 1 < DM / 32) {
      const int nb = ((kt + 1) & 1) * 4096;
      async16(gA0, lA + nb + w * 1024); async16(gA1, lA + nb + w * 1024 + 512);
      async16(gB0, lB + nb + w * 1024); async16(gB1, lB + nb + w * 1024 + 512);
      gA0 += 32; gA1 += 32; gB0 += 32; gB1 += 32;
    }
    const int cb = (kt & 1) * 4096;
    bf16x8 a[4], b[4];
#pragma unroll
    for (int mt = 0; mt < 4; ++mt)
      a[mt] = *(const bf16x8*)&lA[cb + (mrow + mt * 16) * 32 + cswz];
#pragma unroll
    for (int nt = 0; nt < 4; ++nt)
      b[nt] = *(const bf16x8*)&lB[cb + (nrow + nt * 16) * 32 + cswz];
#pragma unroll
    for (int mt = 0; mt < 4; ++mt)
#pragma unroll
      for (int nt = 0; nt < 4; ++nt)
        acc[mt][nt] = __builtin_amdgcn_mfma_f32_16x16x32_bf16(
            a[mt], b[nt], acc[mt][nt], 0, 0, 0);
  }
}

// QKV: z=0 -> Q (pre-scaled by 0.125*log2e); z=1 -> K; z=2 -> V^T
__global__ __launch_bounds__(256) void qkv_kernel(
    const bf16* __restrict__ xb, const bf16* __restrict__ wq,
    const bf16* __restrict__ wk, const bf16* __restrict__ wv,
    bf16* __restrict__ Qb, bf16* __restrict__ Kb, bf16* __restrict__ Vtb) {
  const int z = blockIdx.z;
  const bf16* B = (z == 0) ? wq : (z == 1) ? wk : wv;
  const int m0 = blockIdx.x * 128, n0 = blockIdx.y * 128;
  floatx4 acc[4][4] = {};
  gemm_core(xb, B, m0, n0, acc);
  const int lane = threadIdx.x & 63, w = threadIdx.x >> 6;
  const int quad = lane >> 4, ql = lane & 15;
  const float qs = (z == 0) ? 0.18033688011112042f : 1.0f;  // 0.125*log2(e)
  if (z < 2) {
    bf16* C = (z == 0) ? Qb : Kb;
#pragma unroll
    for (int mt = 0; mt < 4; ++mt)
#pragma unroll
      for (int nt = 0; nt < 4; ++nt) {
        int row = m0 + (w >> 1) * 64 + mt * 16 + quad * 4;
        int col = n0 + (w & 1) * 64 + nt * 16 + ql;
#pragma unroll
        for (int r = 0; r < 4; ++r)
          *(uint16_t*)&C[(size_t)(row + r) * DM + col] = f2bf(acc[mt][nt][r] * qs);
      }
  } else {
#pragma unroll
    for (int mt = 0; mt < 4; ++mt)
#pragma unroll
      for (int nt = 0; nt < 4; ++nt) {
        int row = m0 + (w >> 1) * 64 + mt * 16 + quad * 4;  // s
        int col = n0 + (w & 1) * 64 + nt * 16 + ql;         // d
        uint32_t lo = pk2(acc[mt][nt][0], acc[mt][nt][1]);
        uint32_t hi = pk2(acc[mt][nt][2], acc[mt][nt][3]);
        *(uint2*)&Vtb[(size_t)col * SQ + row] = make_uint2(lo, hi);
      }
  }
}

// output projection, 64x128 tiles (384 blocks), double-buffered staging
__global__ __launch_bounds__(256) void proj_kernel(
    const bf16* __restrict__ Ob, const bf16* __restrict__ wp,
    float* __restrict__ out) {
  __shared__ bf16 lA[2 * 2048];
  __shared__ bf16 lB[2 * 4096];
  const int tid = threadIdx.x, lane = tid & 63, w = tid >> 6;
  const int m0 = blockIdx.x * 64, n0 = blockIdx.y * 128;

  const int ke = (((lane & 3) ^ ((lane >> 3) & 3))) * 8;
  const bf16* gA = Ob + (size_t)(m0 + w * 16 + (lane >> 2)) * DM + ke;
  const bf16* gB0 = wp + (size_t)(n0 + w * 32 + (lane >> 2)) * DM + ke;
  const bf16* gB1 = wp + (size_t)(n0 + w * 32 + (lane >> 2) + 16) * DM + ke;

  async16(gA, lA + w * 512);
  async16(gB0, lB + w * 1024); async16(gB1, lB + w * 1024 + 512);
  gA += 32; gB0 += 32; gB1 += 32;

  const int mrow = (w >> 1) * 32 + (lane & 15);
  const int nrow = (w & 1) * 64 + (lane & 15);
  const int cswz = ((lane >> 4) ^ ((lane >> 1) & 3)) * 8;
  floatx4 acc[2][4] = {};

  for (int kt = 0; kt < DM / 32; ++kt) {
    __syncthreads();
    if (kt + 1 < DM / 32) {
      const int nbA = ((kt + 1) & 1) * 2048, nbB = ((kt + 1) & 1) * 4096;
      async16(gA, lA + nbA + w * 512);
      async16(gB0, lB + nbB + w * 1024); async16(gB1, lB + nbB + w * 1024 + 512);
      gA += 32; gB0 += 32; gB1 += 32;
    }
    const int cbA = (kt & 1) * 2048, cbB = (kt & 1) * 4096;
    bf16x8 a[2], b[4];
#pragma unroll
    for (int mt = 0; mt < 2; ++mt)
      a[mt] = *(const bf16x8*)&lA[cbA + (mrow + mt * 16) * 32 + cswz];
#pragma unroll
    for (int nt = 0; nt < 4; ++nt)
      b[nt] = *(const bf16x8*)&lB[cbB + (nrow + nt * 16) * 32 + cswz];
#pragma unroll
    for (int mt = 0; mt < 2; ++mt)
#pragma unroll
      for (int nt = 0; nt < 4; ++nt)
        acc[mt][nt] = __builtin_amdgcn_mfma_f32_16x16x32_bf16(
            a[mt], b[nt], acc[mt][nt], 0, 0, 0);
  }
  const int quad = lane >> 4, ql = lane & 15;
#pragma unroll
  for (int mt = 0; mt < 2; ++mt)
#pragma unroll
    for (int nt = 0; nt < 4; ++nt) {
      int row = m0 + (w >> 1) * 32 + mt * 16 + quad * 4;
      int col = n0 + (w & 1) * 64 + nt * 16 + ql;
#pragma unroll
      for (int r = 0; r < 4; ++r)
        out[(size_t)(row + r) * DM + col] = acc[mt][nt][r];
    }
}

// ---------------- split-KV causal flash attention (transposed) ------------
// Block tile = 64 q x 64 kv-step, 4 waves = 2 q-halves x 2 kv-halves; each
// wave computes 32q x 32kv and the kv-halves are reduced once per block
// through the free LDS buffer. Grid 1920 blocks (heavy-first table), 32 KB
// LDS -> 5 blocks/CU resident (PROVEN baseline: 45.7 us, VGPR 48).
// setprio around MFMA clusters: measured neutral (R7), kept as harmless.
// Fixed-base softmax (Q pre-scaled): p = exp2(s).
__global__ __launch_bounds__(256, 5) void attn_kernel(
    const bf16* __restrict__ Qb, const bf16* __restrict__ Kb,
    const bf16* __restrict__ Vtb, uint16_t* __restrict__ OpartB,
    float* __restrict__ Lpart, bf16* __restrict__ Ob) {
#if HAVE_MFMA16
  __shared__ __align__(16) char smem[32768];
#else
  __shared__ __align__(16) char smem[40960];
  bf16* lPt = (bf16*)(smem + 32768);  // 8 KB P^T scratch, 2 KB per wave
#endif
  // buffer b (b=0,1) at smem + b*16384: K = 8 KB (2 dchunks [64][32]),
  // V = 8 KB at +8192 (2 kv-chunks [64 d][32 kv]); both source-swizzled.
  const int tid = threadIdx.x, lane = tid & 63, w = tid >> 6;  // w: 0..3
  const int quad = lane >> 4, ql = lane & 15;
  const int qh = w & 1;   // q half  (32 rows)
  const int kh = w >> 1;  // kv half (32 cols)

  int b = blockIdx.x;
  int h = b % NH;
  int i = b / NH;
  int e = kMap.v[i];
  int qb = e >> 2, c = e & 3;
  const int kv0 = c * 1024;
  const int qlen = (qb + 1) * 64;
  const int kv_end = min(qlen, kv0 + 1024);
  const int n_it = (kv_end - kv0) >> 6;  // 1..16
  const bool diag = (kv_end == qlen);

  // Q fragments (pre-scaled), B-operand layout; 32 q rows per wave
  bf16x8 qf[2][2];
#pragma unroll
  for (int nt = 0; nt < 2; ++nt)
#pragma unroll
    for (int kt = 0; kt < 2; ++kt)
      qf[nt][kt] = *(const bf16x8*)&Qb[(size_t)(qb * 64 + qh * 32 + nt * 16 + ql) * DM +
                                       h * 64 + kt * 32 + quad * 8];

  // staging pointers (source-side XOR chunk swizzle); 2 K + 2 V per thread
  const int src_e = (((lane & 3) ^ ((lane >> 3) & 3))) * 8;
  const bf16* gK[2];
  const bf16* gV[2];
#pragma unroll
  for (int t = 0; t < 2; ++t) {
    int o = t * 4096 + w * 1024 + lane * 16;  // byte in 8KB K image
    int cK = o >> 12, rK = (o & 4095) >> 6;
    gK[t] = Kb + (size_t)(kv0 + rK) * DM + h * 64 + cK * 32 + src_e;
    int dV = w * 16 + (lane >> 2);            // V image: [t][dV][32]
    gV[t] = Vtb + (size_t)(h * 64 + dV) * SQ + kv0 + t * 32 + src_e;
  }

  // prologue: stage K(0)+V(0) into buf 0
#pragma unroll
  for (int t = 0; t < 2; ++t) {
    async16(gK[t], (bf16*)(smem + t * 4096 + w * 1024));
    async16(gV[t], (bf16*)(smem + 8192 + t * 4096 + w * 1024));
    gK[t] += 64 * DM;
    gV[t] += 64;
  }

  floatx4 o_acc[4][2] = {};
  float l_s[2] = {0.f, 0.f};
  const int cswz = ((lane >> 4) ^ ((lane >> 1) & 3)) * 8;

  for (int j = 0; j < n_it; ++j) {
    __syncthreads();  // drains (j) tiles staged last iter: full iter of cover
    if (j + 1 < n_it) {
      char* dst = smem + ((j + 1) & 1) * 16384;
#pragma unroll
      for (int t = 0; t < 2; ++t) {
        async16(gK[t], (bf16*)(dst + t * 4096 + w * 1024));
        async16(gV[t], (bf16*)(dst + 8192 + t * 4096 + w * 1024));
        gK[t] += 64 * DM;
        gV[t] += 64;
      }
    }
    const char* cbuf = smem + (j & 1) * 16384;
    const bf16* kbuf = (const bf16*)cbuf;
    const char* vbuf = cbuf + 8192;

    // QK^T: S[32 kv (kh half)][32 q (qh half)]
    floatx4 s[2][2] = {};
    __builtin_amdgcn_s_setprio(1);
#pragma unroll
    for (int kt = 0; kt < 2; ++kt)
#pragma unroll
      for (int mt = 0; mt < 2; ++mt) {
        bf16x8 a = *(const bf16x8*)&kbuf[kt * 2048 + (kh * 32 + mt * 16 + ql) * 32 + cswz];
#pragma unroll
        for (int nt = 0; nt < 2; ++nt)
          s[mt][nt] = __builtin_amdgcn_mfma_f32_16x16x32_bf16(a, qf[nt][kt],
                                                              s[mt][nt], 0, 0, 0);
      }
    __builtin_amdgcn_s_setprio(0);

    // diagonal lives entirely in the last 64-kv iteration (q tile = 64)
    if (diag && j == n_it - 1) {
#pragma unroll
      for (int mt = 0; mt < 2; ++mt)
#pragma unroll
        for (int nt = 0; nt < 2; ++nt) {
          const int qpos = qh * 32 + nt * 16 + ql;
#pragma unroll
          for (int r = 0; r < 4; ++r) {
            int kpos = kh * 32 + mt * 16 + quad * 4 + r;
            if (kpos > qpos) s[mt][nt][r] = -1e30f;
          }
        }
    }

    // fixed-base softmax: exp2 + pack + tree-sum, one pass
    uint2 pp[2][2];
#pragma unroll
    for (int nt = 0; nt < 2; ++nt) {
      float tsum[2];
#pragma unroll
      for (int mt = 0; mt < 2; ++mt) {
        float p0 = __builtin_amdgcn_exp2f(s[mt][nt][0]);
        float p1 = __builtin_amdgcn_exp2f(s[mt][nt][1]);
        float p2 = __builtin_amdgcn_exp2f(s[mt][nt][2]);
        float p3 = __builtin_amdgcn_exp2f(s[mt][nt][3]);
        pp[mt][nt] = make_uint2(pk2(p0, p1), pk2(p2, p3));
        tsum[mt] = (p0 + p1) + (p2 + p3);
      }
      l_s[nt] += tsum[0] + tsum[1];
    }

#if HAVE_MFMA16
    // PV: O^T[d][q] += V^T(kh half) · P^T, B-frags straight from packed regs
    __builtin_amdgcn_s_setprio(1);
#pragma unroll
    for (int mt = 0; mt < 2; ++mt) {
      short4v bfr[2];
#pragma unroll
      for (int nt = 0; nt < 2; ++nt) {
        union { uint2 u; short4v v; } pb;
        pb.u = pp[mt][nt];
        bfr[nt] = pb.v;
      }
      const char* vbase = vbuf + kh * 4096 +
          (((mt * 2 + (quad >> 1)) ^ ((ql >> 1) & 3)) * 16) +
          (quad & 1) * 8;
#pragma unroll
      for (int mtd = 0; mtd < 4; ++mtd) {
        short4v a = *(const short4v*)(vbase + (mtd * 16 + ql) * 64);
#pragma unroll
        for (int nt = 0; nt < 2; ++nt)
          o_acc[mtd][nt] = __builtin_amdgcn_mfma_f32_16x16x16bf16_1k(
              a, bfr[nt], o_acc[mtd][nt], 0, 0, 0);
      }
    }
    __builtin_amdgcn_s_setprio(0);
#else
    // PV via wave-private LDS P^T transpose (one 32-kv group per wave)
    bf16* lp = lPt + w * 1024;  // 2 KB per wave (32 q rows x 64 B)
    {
#pragma unroll
      for (int nt = 0; nt < 2; ++nt) {
        int q32 = nt * 16 + ql;
        int key = (q32 >> 1) & 7;
#pragma unroll
        for (int mtp = 0; mtp < 2; ++mtp) {
          int slot = mtp * 4 + quad;
          *(uint2*)((char*)lp + q32 * 64 + ((slot ^ key) * 8)) = pp[mtp][nt];
        }
      }
      bf16x8 bp[2];
#pragma unroll
      for (int nt = 0; nt < 2; ++nt) {
        int q32 = nt * 16 + ql;
        int key = (q32 >> 1) & 7;
        union { uint2 u[2]; bf16x8 v; } pb;
        pb.u[0] = *(uint2*)((char*)lp + q32 * 64 + (((2 * quad) ^ key) * 8));
        pb.u[1] = *(uint2*)((char*)lp + q32 * 64 + (((2 * quad + 1) ^ key) * 8));
        bp[nt] = pb.v;
      }
      __builtin_amdgcn_s_setprio(1);
#pragma unroll
      for (int mtd = 0; mtd < 4; ++mtd) {
        bf16x8 a = *(const bf16x8*)((const bf16*)vbuf + kh * 2048 +
                                    (mtd * 16 + ql) * 32 + cswz);
#pragma unroll
        for (int nt = 0; nt < 2; ++nt)
          o_acc[mtd][nt] = __builtin_amdgcn_mfma_f32_16x16x32_bf16(
              a, bp[nt], o_acc[mtd][nt], 0, 0, 0);
      }
      __builtin_amdgcn_s_setprio(0);
    }
#endif
  }

  // ---- cross-wave kv-half reduction through the free LDS buffer ----------
  char* fb = smem + ((n_it & 1) * 16384);        // buffer not computed last
  char* lb = smem + (((n_it - 1) & 1) * 16384);  // last-computed buffer
  __syncthreads();  // all PV reads of last buffer done
  if (kh == 1) {
    char* po = fb + (w - 2) * 8192;
#pragma unroll
    for (int nt = 0; nt < 2; ++nt)
#pragma unroll
      for (int mtd = 0; mtd < 4; ++mtd)
        *(floatx4*)(po + (nt * 4 + mtd) * 1024 + lane * 16) = o_acc[mtd][nt];
    float2* pl = (float2*)(lb + (w - 2) * 512);
    pl[lane] = make_float2(l_s[0], l_s[1]);
  }
  __syncthreads();
  if (kh == 0) {
    char* po = fb + w * 8192;
#pragma unroll
    for (int nt = 0; nt < 2; ++nt)
#pragma unroll
      for (int mtd = 0; mtd < 4; ++mtd)
        o_acc[mtd][nt] += *(const floatx4*)(po + (nt * 4 + mtd) * 1024 + lane * 16);
    float2 l2 = ((const float2*)(lb + w * 512))[lane];
    l_s[0] += l2.x;
    l_s[1] += l2.y;

    // finalize l across the 4 lane-groups
    float lf[2];
#pragma unroll
    for (int nt = 0; nt < 2; ++nt) {
      float ls = l_s[nt];
      ls += __shfl_xor(ls, 16);
      ls += __shfl_xor(ls, 32);
      lf[nt] = ls;
    }

    if (qb < 16) {
      // single-chunk tile: normalized direct store
#pragma unroll
      for (int nt = 0; nt < 2; ++nt) {
        float rl = 1.0f / lf[nt];
        int qg = qb * 64 + qh * 32 + nt * 16 + ql;
#pragma unroll
        for (int mtd = 0; mtd < 4; ++mtd) {
          uint32_t lo = pk2(o_acc[mtd][nt][0] * rl, o_acc[mtd][nt][1] * rl);
          uint32_t hi = pk2(o_acc[mtd][nt][2] * rl, o_acc[mtd][nt][3] * rl);
          *(uint2*)&Ob[(size_t)qg * DM + h * 64 + mtd * 16 + quad * 4] =
              make_uint2(lo, hi);
        }
      }
    } else {
      const int ps = (h * 64 + qb) * 4 + c;
#pragma unroll
      for (int nt = 0; nt < 2; ++nt) {
        int q = qh * 32 + nt * 16 + ql;
        if (quad == 0) Lpart[ps * 64 + q] = lf[nt];
#pragma unroll
        for (int mtd = 0; mtd < 4; ++mtd) {
          uint32_t lo = pk2(o_acc[mtd][nt][0], o_acc[mtd][nt][1]);
          uint32_t hi = pk2(o_acc[mtd][nt][2], o_acc[mtd][nt][3]);
          *(uint2*)&OpartB[(size_t)ps * 4096 + q * 64 + mtd * 16 + quad * 4] =
              make_uint2(lo, hi);
        }
      }
    }
  }
}

// merge <=4 bf16 partials per (h, qb>=16) -> Ob (fixed base: plain sums)
__global__ __launch_bounds__(256) void combine_kernel(
    const uint16_t* __restrict__ OpartB, const float* __restrict__ Lpart,
    bf16* __restrict__ Ob) {
  int b = blockIdx.x;                 // 576 = 48 * 12
  int h = b % NH, qb = 16 + b / NH;
  int nch = (qb + 16) >> 4;           // 2..4
  int t = threadIdx.x;
  int q = t >> 2, dh = (t & 3) * 16;  // 64 q x 4 d-slots of 16
  int ps0 = (h * 64 + qb) * 4;

  float acc[16] = {};
  float L = 0.f;
#pragma unroll
  for (int cc = 0; cc < 4; ++cc)
    if (cc < nch) {
      L += Lpart[(ps0 + cc) * 64 + q];
      const uint4* p =
          (const uint4*)(OpartB + (size_t)(ps0 + cc) * 4096 + q * 64 + dh);
#pragma unroll
      for (int g = 0; g < 2; ++g) {
        uint4 u = p[g];
        acc[g * 8 + 0] += bflo(u.x); acc[g * 8 + 1] += bfhi(u.x);
        acc[g * 8 + 2] += bflo(u.y); acc[g * 8 + 3] += bfhi(u.y);
        acc[g * 8 + 4] += bflo(u.z); acc[g * 8 + 5] += bfhi(u.z);
        acc[g * 8 + 6] += bflo(u.w); acc[g * 8 + 7] += bfhi(u.w);
      }
    }
  float rl = 1.0f / L;
  bf16* dst = &Ob[(size_t)(qb * 64 + q) * DM + h * 64 + dh];
#pragma unroll
  for (int g = 0; g < 2; ++g) {
    uint4 u;
    u.x = pk2(acc[g * 8 + 0] * rl, acc[g * 8 + 1] * rl);
    u.y = pk2(acc[g * 8 + 2] * rl, acc[g * 8 + 3] * rl);
    u.z = pk2(acc[g * 8 + 4] * rl, acc[g * 8 + 5] * rl);
    u.w = pk2(acc[g * 8 + 6] * rl, acc[g * 8 + 7] * rl);
    *(uint4*)&dst[g * 8] = u;
  }
}

extern "C" void kernel_launch(void* const* d_in, const int* in_sizes, int n_in,
                              void* d_out, int out_size, void* d_ws,
                              size_t ws_size, hipStream_t stream) {
  const float* x  = (const float*)d_in[0];
  const float* wq = (const float*)d_in[1];
  const float* wk = (const float*)d_in[2];
  const float* wv = (const float*)d_in[3];
  const float* wp = (const float*)d_in[4];
  char* ws = (char*)d_ws;
  // Lpart lives in the xb region (dead after qkv; attn rewrites before
  // combine reads). Peak ws usage = 61341696 B (unchanged layout).
  float* Lpart = (float*)(ws);             // 3072*64*4 = 786432 (inside xb)
  bf16* xb   = (bf16*)(ws);
  bf16* wqb  = (bf16*)(ws + 6291456);
  bf16* wkb  = (bf16*)(ws + 7471104);
  bf16* wvb  = (bf16*)(ws + 8650752);
  bf16* wpb  = (bf16*)(ws + 9830400);
  bf16* Qb   = (bf16*)(ws + 11010048);
  bf16* Kb   = (bf16*)(ws + 17301504);
  bf16* Vtb  = (bf16*)(ws + 23592960);
  bf16* Ob   = (bf16*)(ws + 29884416);
  uint16_t* OpartB = (uint16_t*)(ws + 36175872);  // 3072 x 4096 bf16 -> 61341696

  cvt_kernel<<<5376, 256, 0, stream>>>(x, wq, wk, wv, wp, xb, wqb, wkb, wvb, wpb);
  qkv_kernel<<<dim3(32, 6, 3), 256, 0, stream>>>(xb, wqb, wkb, wvb, Qb, Kb, Vtb);
  attn_kernel<<<1920, 256, 0, stream>>>(Qb, Kb, Vtb, OpartB, Lpart, Ob);
  combine_kernel<<<576, 256, 0, stream>>>(OpartB, Lpart, Ob);
  proj_kernel<<<dim3(64, 6), 256, 0, stream>>>(Ob, wpb, (float*)d_out);
}

// Round 12
// 162.473 us; speedup vs baseline: 1.4845x; 1.0058x over previous
//
#include <hip/hip_runtime.h>
#include <hip/hip_bf16.h>
#include <stdint.h>

#define DM 768
#define SQ 4096
#define NH 12

typedef __bf16 bf16;
typedef __bf16 bf16x8 __attribute__((ext_vector_type(8)));
typedef float floatx4 __attribute__((ext_vector_type(4)));
typedef short short4v __attribute__((ext_vector_type(4)));

#if defined(__has_builtin)
#if __has_builtin(__builtin_amdgcn_mfma_f32_16x16x16bf16_1k)
#define HAVE_MFMA16 1
#endif
#endif
#ifndef HAVE_MFMA16
#define HAVE_MFMA16 0
#endif

typedef __attribute__((address_space(1))) const uint32_t cu32_g;
typedef __attribute__((address_space(3))) uint32_t u32_l;

__device__ __forceinline__ uint16_t f2bf(float f) {
  uint32_t u = __builtin_bit_cast(uint32_t, f);
  u += 0x7fff + ((u >> 16) & 1);
  return (uint16_t)(u >> 16);
}

__device__ __forceinline__ uint32_t pk2(float lo, float hi) {
  __hip_bfloat162 h = __float22bfloat162_rn(float2{lo, hi});
  uint32_t u;
  __builtin_memcpy(&u, &h, 4);
  return u;
}

__device__ __forceinline__ float bflo(uint32_t u) {
  return __builtin_bit_cast(float, u << 16);
}
__device__ __forceinline__ float bfhi(uint32_t u) {
  return __builtin_bit_cast(float, u & 0xffff0000u);
}

// async global->LDS, 16B/lane; LDS dst is wave-uniform base, lane i -> base+i*16
__device__ __forceinline__ void async16(const bf16* g, bf16* l) {
  __builtin_amdgcn_global_load_lds((cu32_g*)g, (u32_l*)l, 16, 0, 0);
}

// ---- heavy-first (qb, c) schedule for 64-q tiles, 2048-kv chunks ----------
// 96 units per head: qb 0..63, chunks c (0..1) with c*2048 < (qb+1)*64.
// Sorted by n_it (64-kv iterations) descending, then qb descending.
// 1152 blocks total <= 1280 resident slots: whole grid co-resident, no
// block-granular second wave. NOTE (R10 lesson): launch-order clustering of
// consecutive units gives the L2 reuse (units sharing KV chunks run
// concurrently); do NOT replace with persistent-block partitioning
// (FETCH 17 -> 131 MB, attn 45.7 -> 123 us).
struct MapT { uint16_t v[96]; };
static constexpr MapT make_map() {
  MapT m{};
  int idx = 0;
  for (int nit = 32; nit >= 1; --nit)
    for (int qb = 63; qb >= 0; --qb) {
      int len = (qb + 1) * 64;
      int nch = (len + 2047) >> 11;
      for (int c = nch - 1; c >= 0; --c) {
        int cs = c * 2048;
        int ce = (len < cs + 2048) ? len : cs + 2048;
        int ni = (ce - cs) >> 6;
        if (ni == nit) m.v[idx++] = (uint16_t)(qb * 4 + c);
      }
    }
  return m;
}
__device__ __constant__ MapT kMap = make_map();

// ---------------- convert fp32 -> bf16 ----------------
__global__ __launch_bounds__(256) void cvt_kernel(
    const float* __restrict__ x, const float* __restrict__ wq,
    const float* __restrict__ wk, const float* __restrict__ wv,
    const float* __restrict__ wp, bf16* __restrict__ xb, bf16* __restrict__ wqb,
    bf16* __restrict__ wkb, bf16* __restrict__ wvb, bf16* __restrict__ wpb) {
  const int XQ = (SQ * DM) / 4;
  const int WQ = (DM * DM) / 4;
  int t = blockIdx.x * 256 + threadIdx.x;
  const float* src;
  bf16* dst;
  int local;
  if (t < XQ) { src = x;  dst = xb;  local = t; }
  else if (t < XQ + WQ)     { src = wq; dst = wqb; local = t - XQ; }
  else if (t < XQ + 2 * WQ) { src = wk; dst = wkb; local = t - XQ - WQ; }
  else if (t < XQ + 3 * WQ) { src = wv; dst = wvb; local = t - XQ - 2 * WQ; }
  else                      { src = wp; dst = wpb; local = t - XQ - 3 * WQ; }
  float4 v = ((const float4*)src)[local];
  ushort4 o;
  o.x = f2bf(v.x); o.y = f2bf(v.y); o.z = f2bf(v.z); o.w = f2bf(v.w);
  ((ushort4*)dst)[local] = o;
}

// ---------------- NT GEMM core 128x128, double-buffered staging -----------
__device__ __forceinline__ void gemm_core(const bf16* __restrict__ A,
                                          const bf16* __restrict__ B, int m0,
                                          int n0, floatx4 (&acc)[4][4]) {
  __shared__ bf16 lA[2 * 4096];
  __shared__ bf16 lB[2 * 4096];
  const int tid = threadIdx.x;
  const int lane = tid & 63;
  const int w = tid >> 6;

  const int r0 = w * 32 + (lane >> 2);
  const int ke = (((lane & 3) ^ ((lane >> 3) & 3))) * 8;  // swizzled src chunk
  const bf16* gA0 = A + (size_t)(m0 + r0) * DM + ke;
  const bf16* gA1 = A + (size_t)(m0 + r0 + 16) * DM + ke;
  const bf16* gB0 = B + (size_t)(n0 + r0) * DM + ke;
  const bf16* gB1 = B + (size_t)(n0 + r0 + 16) * DM + ke;

  async16(gA0, lA + w * 1024); async16(gA1, lA + w * 1024 + 512);
  async16(gB0, lB + w * 1024); async16(gB1, lB + w * 1024 + 512);
  gA0 += 32; gA1 += 32; gB0 += 32; gB1 += 32;

  const int mrow = (w >> 1) * 64 + (lane & 15);
  const int nrow = (w & 1) * 64 + (lane & 15);
  const int cswz = ((lane >> 4) ^ ((lane >> 1) & 3)) * 8;  // swizzled read chunk

  for (int kt = 0; kt < DM / 32; ++kt) {
    __syncthreads();  // drains loads issued last iter (full iter of cover)
    if (kt + 1 < DM / 32) {
      const int nb = ((kt + 1) & 1) * 4096;
      async16(gA0, lA + nb + w * 1024); async16(gA1, lA + nb + w * 1024 + 512);
      async16(gB0, lB + nb + w * 1024); async16(gB1, lB + nb + w * 1024 + 512);
      gA0 += 32; gA1 += 32; gB0 += 32; gB1 += 32;
    }
    const int cb = (kt & 1) * 4096;
    bf16x8 a[4], b[4];
#pragma unroll
    for (int mt = 0; mt < 4; ++mt)
      a[mt] = *(const bf16x8*)&lA[cb + (mrow + mt * 16) * 32 + cswz];
#pragma unroll
    for (int nt = 0; nt < 4; ++nt)
      b[nt] = *(const bf16x8*)&lB[cb + (nrow + nt * 16) * 32 + cswz];
#pragma unroll
    for (int mt = 0; mt < 4; ++mt)
#pragma unroll
      for (int nt = 0; nt < 4; ++nt)
        acc[mt][nt] = __builtin_amdgcn_mfma_f32_16x16x32_bf16(
            a[mt], b[nt], acc[mt][nt], 0, 0, 0);
  }
}

// QKV: z=0 -> Q (pre-scaled by 0.125*log2e); z=1 -> K; z=2 -> V^T
__global__ __launch_bounds__(256) void qkv_kernel(
    const bf16* __restrict__ xb, const bf16* __restrict__ wq,
    const bf16* __restrict__ wk, const bf16* __restrict__ wv,
    bf16* __restrict__ Qb, bf16* __restrict__ Kb, bf16* __restrict__ Vtb) {
  const int z = blockIdx.z;
  const bf16* B = (z == 0) ? wq : (z == 1) ? wk : wv;
  const int m0 = blockIdx.x * 128, n0 = blockIdx.y * 128;
  floatx4 acc[4][4] = {};
  gemm_core(xb, B, m0, n0, acc);
  const int lane = threadIdx.x & 63, w = threadIdx.x >> 6;
  const int quad = lane >> 4, ql = lane & 15;
  const float qs = (z == 0) ? 0.18033688011112042f : 1.0f;  // 0.125*log2(e)
  if (z < 2) {
    bf16* C = (z == 0) ? Qb : Kb;
#pragma unroll
    for (int mt = 0; mt < 4; ++mt)
#pragma unroll
      for (int nt = 0; nt < 4; ++nt) {
        int row = m0 + (w >> 1) * 64 + mt * 16 + quad * 4;
        int col = n0 + (w & 1) * 64 + nt * 16 + ql;
#pragma unroll
        for (int r = 0; r < 4; ++r)
          *(uint16_t*)&C[(size_t)(row + r) * DM + col] = f2bf(acc[mt][nt][r] * qs);
      }
  } else {
#pragma unroll
    for (int mt = 0; mt < 4; ++mt)
#pragma unroll
      for (int nt = 0; nt < 4; ++nt) {
        int row = m0 + (w >> 1) * 64 + mt * 16 + quad * 4;  // s
        int col = n0 + (w & 1) * 64 + nt * 16 + ql;         // d
        uint32_t lo = pk2(acc[mt][nt][0], acc[mt][nt][1]);
        uint32_t hi = pk2(acc[mt][nt][2], acc[mt][nt][3]);
        *(uint2*)&Vtb[(size_t)col * SQ + row] = make_uint2(lo, hi);
      }
  }
}

// output projection, 64x128 tiles (384 blocks), double-buffered staging
__global__ __launch_bounds__(256) void proj_kernel(
    const bf16* __restrict__ Ob, const bf16* __restrict__ wp,
    float* __restrict__ out) {
  __shared__ bf16 lA[2 * 2048];
  __shared__ bf16 lB[2 * 4096];
  const int tid = threadIdx.x, lane = tid & 63, w = tid >> 6;
  const int m0 = blockIdx.x * 64, n0 = blockIdx.y * 128;

  const int ke = (((lane & 3) ^ ((lane >> 3) & 3))) * 8;
  const bf16* gA = Ob + (size_t)(m0 + w * 16 + (lane >> 2)) * DM + ke;
  const bf16* gB0 = wp + (size_t)(n0 + w * 32 + (lane >> 2)) * DM + ke;
  const bf16* gB1 = wp + (size_t)(n0 + w * 32 + (lane >> 2) + 16) * DM + ke;

  async16(gA, lA + w * 512);
  async16(gB0, lB + w * 1024); async16(gB1, lB + w * 1024 + 512);
  gA += 32; gB0 += 32; gB1 += 32;

  const int mrow = (w >> 1) * 32 + (lane & 15);
  const int nrow = (w & 1) * 64 + (lane & 15);
  const int cswz = ((lane >> 4) ^ ((lane >> 1) & 3)) * 8;
  floatx4 acc[2][4] = {};

  for (int kt = 0; kt < DM / 32; ++kt) {
    __syncthreads();
    if (kt + 1 < DM / 32) {
      const int nbA = ((kt + 1) & 1) * 2048, nbB = ((kt + 1) & 1) * 4096;
      async16(gA, lA + nbA + w * 512);
      async16(gB0, lB + nbB + w * 1024); async16(gB1, lB + nbB + w * 1024 + 512);
      gA += 32; gB0 += 32; gB1 += 32;
    }
    const int cbA = (kt & 1) * 2048, cbB = (kt & 1) * 4096;
    bf16x8 a[2], b[4];
#pragma unroll
    for (int mt = 0; mt < 2; ++mt)
      a[mt] = *(const bf16x8*)&lA[cbA + (mrow + mt * 16) * 32 + cswz];
#pragma unroll
    for (int nt = 0; nt < 4; ++nt)
      b[nt] = *(const bf16x8*)&lB[cbB + (nrow + nt * 16) * 32 + cswz];
#pragma unroll
    for (int mt = 0; mt < 2; ++mt)
#pragma unroll
      for (int nt = 0; nt < 4; ++nt)
        acc[mt][nt] = __builtin_amdgcn_mfma_f32_16x16x32_bf16(
            a[mt], b[nt], acc[mt][nt], 0, 0, 0);
  }
  const int quad = lane >> 4, ql = lane & 15;
#pragma unroll
  for (int mt = 0; mt < 2; ++mt)
#pragma unroll
    for (int nt = 0; nt < 4; ++nt) {
      int row = m0 + (w >> 1) * 32 + mt * 16 + quad * 4;
      int col = n0 + (w & 1) * 64 + nt * 16 + ql;
#pragma unroll
      for (int r = 0; r < 4; ++r)
        out[(size_t)(row + r) * DM + col] = acc[mt][nt][r];
    }
}

// ---------------- split-KV causal flash attention (transposed) ------------
// Block tile = 64 q x 64 kv-step, 4 waves = 2 q-halves x 2 kv-halves; each
// wave computes 32q x 32kv and the kv-halves are reduced once per block
// through the free LDS buffer. 2048-kv chunks -> 1152 blocks (heavy-first
// table), 32 KB LDS -> 5 blocks/CU: ENTIRE grid co-resident, no second
// dispatch wave. Partials only for qb>=32 (exactly 2 chunks).
// setprio around MFMA clusters: measured neutral (R7), kept as harmless.
// Fixed-base softmax (Q pre-scaled): p = exp2(s).
__global__ __launch_bounds__(256, 5) void attn_kernel(
    const bf16* __restrict__ Qb, const bf16* __restrict__ Kb,
    const bf16* __restrict__ Vtb, uint16_t* __restrict__ OpartB,
    float* __restrict__ Lpart, bf16* __restrict__ Ob) {
#if HAVE_MFMA16
  __shared__ __align__(16) char smem[32768];
#else
  __shared__ __align__(16) char smem[40960];
  bf16* lPt = (bf16*)(smem + 32768);  // 8 KB P^T scratch, 2 KB per wave
#endif
  // buffer b (b=0,1) at smem + b*16384: K = 8 KB (2 dchunks [64][32]),
  // V = 8 KB at +8192 (2 kv-chunks [64 d][32 kv]); both source-swizzled.
  const int tid = threadIdx.x, lane = tid & 63, w = tid >> 6;  // w: 0..3
  const int quad = lane >> 4, ql = lane & 15;
  const int qh = w & 1;   // q half  (32 rows)
  const int kh = w >> 1;  // kv half (32 cols)

  int b = blockIdx.x;
  int h = b % NH;
  int i = b / NH;
  int e = kMap.v[i];
  int qb = e >> 2, c = e & 3;
  const int kv0 = c * 2048;
  const int qlen = (qb + 1) * 64;
  const int kv_end = min(qlen, kv0 + 2048);
  const int n_it = (kv_end - kv0) >> 6;  // 1..32
  const bool diag = (kv_end == qlen);

  // Q fragments (pre-scaled), B-operand layout; 32 q rows per wave
  bf16x8 qf[2][2];
#pragma unroll
  for (int nt = 0; nt < 2; ++nt)
#pragma unroll
    for (int kt = 0; kt < 2; ++kt)
      qf[nt][kt] = *(const bf16x8*)&Qb[(size_t)(qb * 64 + qh * 32 + nt * 16 + ql) * DM +
                                       h * 64 + kt * 32 + quad * 8];

  // staging pointers (source-side XOR chunk swizzle); 2 K + 2 V per thread
  const int src_e = (((lane & 3) ^ ((lane >> 3) & 3))) * 8;
  const bf16* gK[2];
  const bf16* gV[2];
#pragma unroll
  for (int t = 0; t < 2; ++t) {
    int o = t * 4096 + w * 1024 + lane * 16;  // byte in 8KB K image
    int cK = o >> 12, rK = (o & 4095) >> 6;
    gK[t] = Kb + (size_t)(kv0 + rK) * DM + h * 64 + cK * 32 + src_e;
    int dV = w * 16 + (lane >> 2);            // V image: [t][dV][32]
    gV[t] = Vtb + (size_t)(h * 64 + dV) * SQ + kv0 + t * 32 + src_e;
  }

  // prologue: stage K(0)+V(0) into buf 0
#pragma unroll
  for (int t = 0; t < 2; ++t) {
    async16(gK[t], (bf16*)(smem + t * 4096 + w * 1024));
    async16(gV[t], (bf16*)(smem + 8192 + t * 4096 + w * 1024));
    gK[t] += 64 * DM;
    gV[t] += 64;
  }

  floatx4 o_acc[4][2] = {};
  float l_s[2] = {0.f, 0.f};
  const int cswz = ((lane >> 4) ^ ((lane >> 1) & 3)) * 8;

  for (int j = 0; j < n_it; ++j) {
    __syncthreads();  // drains (j) tiles staged last iter: full iter of cover
    if (j + 1 < n_it) {
      char* dst = smem + ((j + 1) & 1) * 16384;
#pragma unroll
      for (int t = 0; t < 2; ++t) {
        async16(gK[t], (bf16*)(dst + t * 4096 + w * 1024));
        async16(gV[t], (bf16*)(dst + 8192 + t * 4096 + w * 1024));
        gK[t] += 64 * DM;
        gV[t] += 64;
      }
    }
    const char* cbuf = smem + (j & 1) * 16384;
    const bf16* kbuf = (const bf16*)cbuf;
    const char* vbuf = cbuf + 8192;

    // QK^T: S[32 kv (kh half)][32 q (qh half)]
    floatx4 s[2][2] = {};
    __builtin_amdgcn_s_setprio(1);
#pragma unroll
    for (int kt = 0; kt < 2; ++kt)
#pragma unroll
      for (int mt = 0; mt < 2; ++mt) {
        bf16x8 a = *(const bf16x8*)&kbuf[kt * 2048 + (kh * 32 + mt * 16 + ql) * 32 + cswz];
#pragma unroll
        for (int nt = 0; nt < 2; ++nt)
          s[mt][nt] = __builtin_amdgcn_mfma_f32_16x16x32_bf16(a, qf[nt][kt],
                                                              s[mt][nt], 0, 0, 0);
      }
    __builtin_amdgcn_s_setprio(0);

    // diagonal lives entirely in the last 64-kv iteration (q tile = 64)
    if (diag && j == n_it - 1) {
#pragma unroll
      for (int mt = 0; mt < 2; ++mt)
#pragma unroll
        for (int nt = 0; nt < 2; ++nt) {
          const int qpos = qh * 32 + nt * 16 + ql;
#pragma unroll
          for (int r = 0; r < 4; ++r) {
            int kpos = kh * 32 + mt * 16 + quad * 4 + r;
            if (kpos > qpos) s[mt][nt][r] = -1e30f;
          }
        }
    }

    // fixed-base softmax: exp2 + pack + tree-sum, one pass
    uint2 pp[2][2];
#pragma unroll
    for (int nt = 0; nt < 2; ++nt) {
      float tsum[2];
#pragma unroll
      for (int mt = 0; mt < 2; ++mt) {
        float p0 = __builtin_amdgcn_exp2f(s[mt][nt][0]);
        float p1 = __builtin_amdgcn_exp2f(s[mt][nt][1]);
        float p2 = __builtin_amdgcn_exp2f(s[mt][nt][2]);
        float p3 = __builtin_amdgcn_exp2f(s[mt][nt][3]);
        pp[mt][nt] = make_uint2(pk2(p0, p1), pk2(p2, p3));
        tsum[mt] = (p0 + p1) + (p2 + p3);
      }
      l_s[nt] += tsum[0] + tsum[1];
    }

#if HAVE_MFMA16
    // PV: O^T[d][q] += V^T(kh half) · P^T, B-frags straight from packed regs
    __builtin_amdgcn_s_setprio(1);
#pragma unroll
    for (int mt = 0; mt < 2; ++mt) {
      short4v bfr[2];
#pragma unroll
      for (int nt = 0; nt < 2; ++nt) {
        union { uint2 u; short4v v; } pb;
        pb.u = pp[mt][nt];
        bfr[nt] = pb.v;
      }
      const char* vbase = vbuf + kh * 4096 +
          (((mt * 2 + (quad >> 1)) ^ ((ql >> 1) & 3)) * 16) +
          (quad & 1) * 8;
#pragma unroll
      for (int mtd = 0; mtd < 4; ++mtd) {
        short4v a = *(const short4v*)(vbase + (mtd * 16 + ql) * 64);
#pragma unroll
        for (int nt = 0; nt < 2; ++nt)
          o_acc[mtd][nt] = __builtin_amdgcn_mfma_f32_16x16x16bf16_1k(
              a, bfr[nt], o_acc[mtd][nt], 0, 0, 0);
      }
    }
    __builtin_amdgcn_s_setprio(0);
#else
    // PV via wave-private LDS P^T transpose (one 32-kv group per wave)
    bf16* lp = lPt + w * 1024;  // 2 KB per wave (32 q rows x 64 B)
    {
#pragma unroll
      for (int nt = 0; nt < 2; ++nt) {
        int q32 = nt * 16 + ql;
        int key = (q32 >> 1) & 7;
#pragma unroll
        for (int mtp = 0; mtp < 2; ++mtp) {
          int slot = mtp * 4 + quad;
          *(uint2*)((char*)lp + q32 * 64 + ((slot ^ key) * 8)) = pp[mtp][nt];
        }
      }
      bf16x8 bp[2];
#pragma unroll
      for (int nt = 0; nt < 2; ++nt) {
        int q32 = nt * 16 + ql;
        int key = (q32 >> 1) & 7;
        union { uint2 u[2]; bf16x8 v; } pb;
        pb.u[0] = *(uint2*)((char*)lp + q32 * 64 + (((2 * quad) ^ key) * 8));
        pb.u[1] = *(uint2*)((char*)lp + q32 * 64 + (((2 * quad + 1) ^ key) * 8));
        bp[nt] = pb.v;
      }
      __builtin_amdgcn_s_setprio(1);
#pragma unroll
      for (int mtd = 0; mtd < 4; ++mtd) {
        bf16x8 a = *(const bf16x8*)((const bf16*)vbuf + kh * 2048 +
                                    (mtd * 16 + ql) * 32 + cswz);
#pragma unroll
        for (int nt = 0; nt < 2; ++nt)
          o_acc[mtd][nt] = __builtin_amdgcn_mfma_f32_16x16x32_bf16(
              a, bp[nt], o_acc[mtd][nt], 0, 0, 0);
      }
      __builtin_amdgcn_s_setprio(0);
    }
#endif
  }

  // ---- cross-wave kv-half reduction through the free LDS buffer ----------
  char* fb = smem + ((n_it & 1) * 16384);        // buffer not computed last
  char* lb = smem + (((n_it - 1) & 1) * 16384);  // last-computed buffer
  __syncthreads();  // all PV reads of last buffer done
  if (kh == 1) {
    char* po = fb + (w - 2) * 8192;
#pragma unroll
    for (int nt = 0; nt < 2; ++nt)
#pragma unroll
      for (int mtd = 0; mtd < 4; ++mtd)
        *(floatx4*)(po + (nt * 4 + mtd) * 1024 + lane * 16) = o_acc[mtd][nt];
    float2* pl = (float2*)(lb + (w - 2) * 512);
    pl[lane] = make_float2(l_s[0], l_s[1]);
  }
  __syncthreads();
  if (kh == 0) {
    char* po = fb + w * 8192;
#pragma unroll
    for (int nt = 0; nt < 2; ++nt)
#pragma unroll
      for (int mtd = 0; mtd < 4; ++mtd)
        o_acc[mtd][nt] += *(const floatx4*)(po + (nt * 4 + mtd) * 1024 + lane * 16);
    float2 l2 = ((const float2*)(lb + w * 512))[lane];
    l_s[0] += l2.x;
    l_s[1] += l2.y;

    // finalize l across the 4 lane-groups
    float lf[2];
#pragma unroll
    for (int nt = 0; nt < 2; ++nt) {
      float ls = l_s[nt];
      ls += __shfl_xor(ls, 16);
      ls += __shfl_xor(ls, 32);
      lf[nt] = ls;
    }

    if (qb < 32) {
      // single-chunk tile: normalized direct store
#pragma unroll
      for (int nt = 0; nt < 2; ++nt) {
        float rl = 1.0f / lf[nt];
        int qg = qb * 64 + qh * 32 + nt * 16 + ql;
#pragma unroll
        for (int mtd = 0; mtd < 4; ++mtd) {
          uint32_t lo = pk2(o_acc[mtd][nt][0] * rl, o_acc[mtd][nt][1] * rl);
          uint32_t hi = pk2(o_acc[mtd][nt][2] * rl, o_acc[mtd][nt][3] * rl);
          *(uint2*)&Ob[(size_t)qg * DM + h * 64 + mtd * 16 + quad * 4] =
              make_uint2(lo, hi);
        }
      }
    } else {
      const int ps = (h * 64 + qb) * 2 + c;
#pragma unroll
      for (int nt = 0; nt < 2; ++nt) {
        int q = qh * 32 + nt * 16 + ql;
        if (quad == 0) Lpart[ps * 64 + q] = lf[nt];
#pragma unroll
        for (int mtd = 0; mtd < 4; ++mtd) {
          uint32_t lo = pk2(o_acc[mtd][nt][0], o_acc[mtd][nt][1]);
          uint32_t hi = pk2(o_acc[mtd][nt][2], o_acc[mtd][nt][3]);
          *(uint2*)&OpartB[(size_t)ps * 4096 + q * 64 + mtd * 16 + quad * 4] =
              make_uint2(lo, hi);
        }
      }
    }
  }
}

// merge exactly 2 bf16 partials per (h, qb>=32) -> Ob (fixed base: plain sums)
__global__ __launch_bounds__(256) void combine_kernel(
    const uint16_t* __restrict__ OpartB, const float* __restrict__ Lpart,
    bf16* __restrict__ Ob) {
  int b = blockIdx.x;                 // 384 = 32 * 12
  int h = b % NH, qb = 32 + b / NH;
  int t = threadIdx.x;
  int q = t >> 2, dh = (t & 3) * 16;  // 64 q x 4 d-slots of 16
  int ps0 = (h * 64 + qb) * 2;

  float acc[16] = {};
  float L = 0.f;
#pragma unroll
  for (int cc = 0; cc < 2; ++cc) {
    L += Lpart[(ps0 + cc) * 64 + q];
    const uint4* p =
        (const uint4*)(OpartB + (size_t)(ps0 + cc) * 4096 + q * 64 + dh);
#pragma unroll
    for (int g = 0; g < 2; ++g) {
      uint4 u = p[g];
      acc[g * 8 + 0] += bflo(u.x); acc[g * 8 + 1] += bfhi(u.x);
      acc[g * 8 + 2] += bflo(u.y); acc[g * 8 + 3] += bfhi(u.y);
      acc[g * 8 + 4] += bflo(u.z); acc[g * 8 + 5] += bfhi(u.z);
      acc[g * 8 + 6] += bflo(u.w); acc[g * 8 + 7] += bfhi(u.w);
    }
  }
  float rl = 1.0f / L;
  bf16* dst = &Ob[(size_t)(qb * 64 + q) * DM + h * 64 + dh];
#pragma unroll
  for (int g = 0; g < 2; ++g) {
    uint4 u;
    u.x = pk2(acc[g * 8 + 0] * rl, acc[g * 8 + 1] * rl);
    u.y = pk2(acc[g * 8 + 2] * rl, acc[g * 8 + 3] * rl);
    u.z = pk2(acc[g * 8 + 4] * rl, acc[g * 8 + 5] * rl);
    u.w = pk2(acc[g * 8 + 6] * rl, acc[g * 8 + 7] * rl);
    *(uint4*)&dst[g * 8] = u;
  }
}

extern "C" void kernel_launch(void* const* d_in, const int* in_sizes, int n_in,
                              void* d_out, int out_size, void* d_ws,
                              size_t ws_size, hipStream_t stream) {
  const float* x  = (const float*)d_in[0];
  const float* wq = (const float*)d_in[1];
  const float* wk = (const float*)d_in[2];
  const float* wv = (const float*)d_in[3];
  const float* wp = (const float*)d_in[4];
  char* ws = (char*)d_ws;
  // Lpart lives in the xb region (dead after qkv; attn rewrites before
  // combine reads). Peak ws usage = 48771072 B.
  float* Lpart = (float*)(ws);             // 1536*64*4 = 393216 (inside xb)
  bf16* xb   = (bf16*)(ws);
  bf16* wqb  = (bf16*)(ws + 6291456);
  bf16* wkb  = (bf16*)(ws + 7471104);
  bf16* wvb  = (bf16*)(ws + 8650752);
  bf16* wpb  = (bf16*)(ws + 9830400);
  bf16* Qb   = (bf16*)(ws + 11010048);
  bf16* Kb   = (bf16*)(ws + 17301504);
  bf16* Vtb  = (bf16*)(ws + 23592960);
  bf16* Ob   = (bf16*)(ws + 29884416);
  uint16_t* OpartB = (uint16_t*)(ws + 36175872);  // 1536 x 4096 bf16 -> 48771072

  cvt_kernel<<<5376, 256, 0, stream>>>(x, wq, wk, wv, wp, xb, wqb, wkb, wvb, wpb);
  qkv_kernel<<<dim3(32, 6, 3), 256, 0, stream>>>(xb, wqb, wkb, wvb, Qb, Kb, Vtb);
  attn_kernel<<<1152, 256, 0, stream>>>(Qb, Kb, Vtb, OpartB, Lpart, Ob);
  combine_kernel<<<384, 256, 0, stream>>>(OpartB, Lpart, Ob);
  proj_kernel<<<dim3(64, 6), 256, 0, stream>>>(Ob, wpb, (float*)d_out);
}

// Round 13
// 161.118 us; speedup vs baseline: 1.4970x; 1.0084x over previous
//
#include <hip/hip_runtime.h>
#include <hip/hip_bf16.h>
#include <stdint.h>

#define DM 768
#define SQ 4096
#define NH 12

typedef __bf16 bf16;
typedef __bf16 bf16x8 __attribute__((ext_vector_type(8)));
typedef float floatx4 __attribute__((ext_vector_type(4)));
typedef short short4v __attribute__((ext_vector_type(4)));

#if defined(__has_builtin)
#if __has_builtin(__builtin_amdgcn_mfma_f32_16x16x16bf16_1k)
#define HAVE_MFMA16 1
#endif
#endif
#ifndef HAVE_MFMA16
#define HAVE_MFMA16 0
#endif

typedef __attribute__((address_space(1))) const uint32_t cu32_g;
typedef __attribute__((address_space(3))) uint32_t u32_l;

__device__ __forceinline__ uint16_t f2bf(float f) {
  uint32_t u = __builtin_bit_cast(uint32_t, f);
  u += 0x7fff + ((u >> 16) & 1);
  return (uint16_t)(u >> 16);
}

__device__ __forceinline__ uint32_t pk2(float lo, float hi) {
  __hip_bfloat162 h = __float22bfloat162_rn(float2{lo, hi});
  uint32_t u;
  __builtin_memcpy(&u, &h, 4);
  return u;
}

__device__ __forceinline__ float bflo(uint32_t u) {
  return __builtin_bit_cast(float, u << 16);
}
__device__ __forceinline__ float bfhi(uint32_t u) {
  return __builtin_bit_cast(float, u & 0xffff0000u);
}

// async global->LDS, 16B/lane; LDS dst is wave-uniform base, lane i -> base+i*16
__device__ __forceinline__ void async16(const bf16* g, bf16* l) {
  __builtin_amdgcn_global_load_lds((cu32_g*)g, (u32_l*)l, 16, 0, 0);
}

// ---- heavy-first (qb, c) schedule for 64-q tiles, 2048-kv chunks ----------
// 96 units per head: qb 0..63, chunks c (0..1) with c*2048 < (qb+1)*64.
// Sorted by n_it (64-kv iterations) descending, then qb descending.
// 1152 blocks total <= 1280 resident slots: whole grid co-resident, no
// block-granular second wave. NOTE (R10 lesson): launch-order clustering of
// consecutive units gives the L2 reuse (units sharing KV chunks run
// concurrently); do NOT replace with persistent-block partitioning
// (FETCH 17 -> 131 MB, attn 45.7 -> 123 us).
struct MapT { uint16_t v[96]; };
static constexpr MapT make_map() {
  MapT m{};
  int idx = 0;
  for (int nit = 32; nit >= 1; --nit)
    for (int qb = 63; qb >= 0; --qb) {
      int len = (qb + 1) * 64;
      int nch = (len + 2047) >> 11;
      for (int c = nch - 1; c >= 0; --c) {
        int cs = c * 2048;
        int ce = (len < cs + 2048) ? len : cs + 2048;
        int ni = (ce - cs) >> 6;
        if (ni == nit) m.v[idx++] = (uint16_t)(qb * 4 + c);
      }
    }
  return m;
}
__device__ __constant__ MapT kMap = make_map();

// ---------------- convert fp32 -> bf16 ----------------
__global__ __launch_bounds__(256) void cvt_kernel(
    const float* __restrict__ x, const float* __restrict__ wq,
    const float* __restrict__ wk, const float* __restrict__ wv,
    const float* __restrict__ wp, bf16* __restrict__ xb, bf16* __restrict__ wqb,
    bf16* __restrict__ wkb, bf16* __restrict__ wvb, bf16* __restrict__ wpb) {
  const int XQ = (SQ * DM) / 4;
  const int WQ = (DM * DM) / 4;
  int t = blockIdx.x * 256 + threadIdx.x;
  const float* src;
  bf16* dst;
  int local;
  if (t < XQ) { src = x;  dst = xb;  local = t; }
  else if (t < XQ + WQ)     { src = wq; dst = wqb; local = t - XQ; }
  else if (t < XQ + 2 * WQ) { src = wk; dst = wkb; local = t - XQ - WQ; }
  else if (t < XQ + 3 * WQ) { src = wv; dst = wvb; local = t - XQ - 2 * WQ; }
  else                      { src = wp; dst = wpb; local = t - XQ - 3 * WQ; }
  float4 v = ((const float4*)src)[local];
  ushort4 o;
  o.x = f2bf(v.x); o.y = f2bf(v.y); o.z = f2bf(v.z); o.w = f2bf(v.w);
  ((ushort4*)dst)[local] = o;
}

// ---------------- NT GEMM core 128x128, double-buffered staging -----------
__device__ __forceinline__ void gemm_core(const bf16* __restrict__ A,
                                          const bf16* __restrict__ B, int m0,
                                          int n0, floatx4 (&acc)[4][4]) {
  __shared__ bf16 lA[2 * 4096];
  __shared__ bf16 lB[2 * 4096];
  const int tid = threadIdx.x;
  const int lane = tid & 63;
  const int w = tid >> 6;

  const int r0 = w * 32 + (lane >> 2);
  const int ke = (((lane & 3) ^ ((lane >> 3) & 3))) * 8;  // swizzled src chunk
  const bf16* gA0 = A + (size_t)(m0 + r0) * DM + ke;
  const bf16* gA1 = A + (size_t)(m0 + r0 + 16) * DM + ke;
  const bf16* gB0 = B + (size_t)(n0 + r0) * DM + ke;
  const bf16* gB1 = B + (size_t)(n0 + r0 + 16) * DM + ke;

  async16(gA0, lA + w * 1024); async16(gA1, lA + w * 1024 + 512);
  async16(gB0, lB + w * 1024); async16(gB1, lB + w * 1024 + 512);
  gA0 += 32; gA1 += 32; gB0 += 32; gB1 += 32;

  const int mrow = (w >> 1) * 64 + (lane & 15);
  const int nrow = (w & 1) * 64 + (lane & 15);
  const int cswz = ((lane >> 4) ^ ((lane >> 1) & 3)) * 8;  // swizzled read chunk

  for (int kt = 0; kt < DM / 32; ++kt) {
    __syncthreads();  // drains loads issued last iter (full iter of cover)
    if (kt + 1 < DM / 32) {
      const int nb = ((kt + 1) & 1) * 4096;
      async16(gA0, lA + nb + w * 1024); async16(gA1, lA + nb + w * 1024 + 512);
      async16(gB0, lB + nb + w * 1024); async16(gB1, lB + nb + w * 1024 + 512);
      gA0 += 32; gA1 += 32; gB0 += 32; gB1 += 32;
    }
    const int cb = (kt & 1) * 4096;
    bf16x8 a[4], b[4];
#pragma unroll
    for (int mt = 0; mt < 4; ++mt)
      a[mt] = *(const bf16x8*)&lA[cb + (mrow + mt * 16) * 32 + cswz];
#pragma unroll
    for (int nt = 0; nt < 4; ++nt)
      b[nt] = *(const bf16x8*)&lB[cb + (nrow + nt * 16) * 32 + cswz];
#pragma unroll
    for (int mt = 0; mt < 4; ++mt)
#pragma unroll
      for (int nt = 0; nt < 4; ++nt)
        acc[mt][nt] = __builtin_amdgcn_mfma_f32_16x16x32_bf16(
            a[mt], b[nt], acc[mt][nt], 0, 0, 0);
  }
}

// QKV: z=0 -> Q (pre-scaled by 0.125*log2e); z=1 -> K; z=2 -> V^T
__global__ __launch_bounds__(256) void qkv_kernel(
    const bf16* __restrict__ xb, const bf16* __restrict__ wq,
    const bf16* __restrict__ wk, const bf16* __restrict__ wv,
    bf16* __restrict__ Qb, bf16* __restrict__ Kb, bf16* __restrict__ Vtb) {
  const int z = blockIdx.z;
  const bf16* B = (z == 0) ? wq : (z == 1) ? wk : wv;
  const int m0 = blockIdx.x * 128, n0 = blockIdx.y * 128;
  floatx4 acc[4][4] = {};
  gemm_core(xb, B, m0, n0, acc);
  const int lane = threadIdx.x & 63, w = threadIdx.x >> 6;
  const int quad = lane >> 4, ql = lane & 15;
  const float qs = (z == 0) ? 0.18033688011112042f : 1.0f;  // 0.125*log2(e)
  if (z < 2) {
    bf16* C = (z == 0) ? Qb : Kb;
#pragma unroll
    for (int mt = 0; mt < 4; ++mt)
#pragma unroll
      for (int nt = 0; nt < 4; ++nt) {
        int row = m0 + (w >> 1) * 64 + mt * 16 + quad * 4;
        int col = n0 + (w & 1) * 64 + nt * 16 + ql;
#pragma unroll
        for (int r = 0; r < 4; ++r)
          *(uint16_t*)&C[(size_t)(row + r) * DM + col] = f2bf(acc[mt][nt][r] * qs);
      }
  } else {
#pragma unroll
    for (int mt = 0; mt < 4; ++mt)
#pragma unroll
      for (int nt = 0; nt < 4; ++nt) {
        int row = m0 + (w >> 1) * 64 + mt * 16 + quad * 4;  // s
        int col = n0 + (w & 1) * 64 + nt * 16 + ql;         // d
        uint32_t lo = pk2(acc[mt][nt][0], acc[mt][nt][1]);
        uint32_t hi = pk2(acc[mt][nt][2], acc[mt][nt][3]);
        *(uint2*)&Vtb[(size_t)col * SQ + row] = make_uint2(lo, hi);
      }
  }
}

// output projection, 64x128 tiles (384 blocks), double-buffered staging.
// R13: combine fused into the A-staging — for qb>=32 (rows whose attention
// used 2 kv chunks), stage A by reading both OpartB partials + Lpart,
// merging/normalizing in registers and ds_writing the SAME swizzled layout
// async16 would produce. combine_kernel deleted; Ob round-trip removed.
__global__ __launch_bounds__(256) void proj_kernel(
    const bf16* __restrict__ Ob, const bf16* __restrict__ wp,
    const uint16_t* __restrict__ OpartB, const float* __restrict__ Lpart,
    float* __restrict__ out) {
  __shared__ bf16 lA[2 * 2048];
  __shared__ bf16 lB[2 * 4096];
  const int tid = threadIdx.x, lane = tid & 63, w = tid >> 6;
  const int qb = blockIdx.x;          // 64-row A-tile == one qb
  const int m0 = qb * 64, n0 = blockIdx.y * 128;
  const bool merged = (qb >= 32);

  const int ke = (((lane & 3) ^ ((lane >> 3) & 3))) * 8;
  const int arow = w * 16 + (lane >> 2);  // q within tile, fixed per thread
  const bf16* gA = Ob + (size_t)(m0 + arow) * DM + ke;
  const bf16* gB0 = wp + (size_t)(n0 + w * 32 + (lane >> 2)) * DM + ke;
  const bf16* gB1 = wp + (size_t)(n0 + w * 32 + (lane >> 2) + 16) * DM + ke;

  // stage A-tile k-slice kt into lA half nbA (elements)
  auto stageA = [&](int kt, int nbA) {
    if (!merged) {
      async16(gA + kt * 32, lA + nbA + w * 512);
    } else {
      int col = kt * 32 + ke;           // global k-col, 0..767
      int hh = col >> 6, dih = col & 63;
      int ps0 = (hh * 64 + qb) * 2;
      uint4 u0 = *(const uint4*)(OpartB + (size_t)ps0 * 4096 + arow * 64 + dih);
      uint4 u1 = *(const uint4*)(OpartB + (size_t)(ps0 + 1) * 4096 + arow * 64 + dih);
      float rl = 1.0f / (Lpart[ps0 * 64 + arow] + Lpart[(ps0 + 1) * 64 + arow]);
      uint4 o;
      o.x = pk2((bflo(u0.x) + bflo(u1.x)) * rl, (bfhi(u0.x) + bfhi(u1.x)) * rl);
      o.y = pk2((bflo(u0.y) + bflo(u1.y)) * rl, (bfhi(u0.y) + bfhi(u1.y)) * rl);
      o.z = pk2((bflo(u0.z) + bflo(u1.z)) * rl, (bfhi(u0.z) + bfhi(u1.z)) * rl);
      o.w = pk2((bflo(u0.w) + bflo(u1.w)) * rl, (bfhi(u0.w) + bfhi(u1.w)) * rl);
      *(uint4*)(lA + nbA + w * 512 + lane * 8) = o;  // lane*16B, async16 layout
    }
  };

  stageA(0, 0);
  async16(gB0, lB + w * 1024); async16(gB1, lB + w * 1024 + 512);
  gB0 += 32; gB1 += 32;

  const int mrow = (w >> 1) * 32 + (lane & 15);
  const int nrow = (w & 1) * 64 + (lane & 15);
  const int cswz = ((lane >> 4) ^ ((lane >> 1) & 3)) * 8;
  floatx4 acc[2][4] = {};

  for (int kt = 0; kt < DM / 32; ++kt) {
    __syncthreads();
    if (kt + 1 < DM / 32) {
      const int nbA = ((kt + 1) & 1) * 2048, nbB = ((kt + 1) & 1) * 4096;
      stageA(kt + 1, nbA);
      async16(gB0, lB + nbB + w * 1024); async16(gB1, lB + nbB + w * 1024 + 512);
      gB0 += 32; gB1 += 32;
    }
    const int cbA = (kt & 1) * 2048, cbB = (kt & 1) * 4096;
    bf16x8 a[2], b[4];
#pragma unroll
    for (int mt = 0; mt < 2; ++mt)
      a[mt] = *(const bf16x8*)&lA[cbA + (mrow + mt * 16) * 32 + cswz];
#pragma unroll
    for (int nt = 0; nt < 4; ++nt)
      b[nt] = *(const bf16x8*)&lB[cbB + (nrow + nt * 16) * 32 + cswz];
#pragma unroll
    for (int mt = 0; mt < 2; ++mt)
#pragma unroll
      for (int nt = 0; nt < 4; ++nt)
        acc[mt][nt] = __builtin_amdgcn_mfma_f32_16x16x32_bf16(
            a[mt], b[nt], acc[mt][nt], 0, 0, 0);
  }
  const int quad = lane >> 4, ql = lane & 15;
#pragma unroll
  for (int mt = 0; mt < 2; ++mt)
#pragma unroll
    for (int nt = 0; nt < 4; ++nt) {
      int row = m0 + (w >> 1) * 32 + mt * 16 + quad * 4;
      int col = n0 + (w & 1) * 64 + nt * 16 + ql;
#pragma unroll
      for (int r = 0; r < 4; ++r)
        out[(size_t)(row + r) * DM + col] = acc[mt][nt][r];
    }
}

// ---------------- split-KV causal flash attention (transposed) ------------
// Block tile = 64 q x 64 kv-step, 4 waves = 2 q-halves x 2 kv-halves; each
// wave computes 32q x 32kv and the kv-halves are reduced once per block
// through the free LDS buffer. 2048-kv chunks -> 1152 blocks (heavy-first
// table), 32 KB LDS -> 5 blocks/CU: ENTIRE grid co-resident, no second
// dispatch wave. Partials only for qb>=32 (exactly 2 chunks; merged by proj).
// setprio around MFMA clusters: measured neutral (R7), kept as harmless.
// Fixed-base softmax (Q pre-scaled): p = exp2(s).
__global__ __launch_bounds__(256, 5) void attn_kernel(
    const bf16* __restrict__ Qb, const bf16* __restrict__ Kb,
    const bf16* __restrict__ Vtb, uint16_t* __restrict__ OpartB,
    float* __restrict__ Lpart, bf16* __restrict__ Ob) {
#if HAVE_MFMA16
  __shared__ __align__(16) char smem[32768];
#else
  __shared__ __align__(16) char smem[40960];
  bf16* lPt = (bf16*)(smem + 32768);  // 8 KB P^T scratch, 2 KB per wave
#endif
  // buffer b (b=0,1) at smem + b*16384: K = 8 KB (2 dchunks [64][32]),
  // V = 8 KB at +8192 (2 kv-chunks [64 d][32 kv]); both source-swizzled.
  const int tid = threadIdx.x, lane = tid & 63, w = tid >> 6;  // w: 0..3
  const int quad = lane >> 4, ql = lane & 15;
  const int qh = w & 1;   // q half  (32 rows)
  const int kh = w >> 1;  // kv half (32 cols)

  int b = blockIdx.x;
  int h = b % NH;
  int i = b / NH;
  int e = kMap.v[i];
  int qb = e >> 2, c = e & 3;
  const int kv0 = c * 2048;
  const int qlen = (qb + 1) * 64;
  const int kv_end = min(qlen, kv0 + 2048);
  const int n_it = (kv_end - kv0) >> 6;  // 1..32
  const bool diag = (kv_end == qlen);

  // Q fragments (pre-scaled), B-operand layout; 32 q rows per wave
  bf16x8 qf[2][2];
#pragma unroll
  for (int nt = 0; nt < 2; ++nt)
#pragma unroll
    for (int kt = 0; kt < 2; ++kt)
      qf[nt][kt] = *(const bf16x8*)&Qb[(size_t)(qb * 64 + qh * 32 + nt * 16 + ql) * DM +
                                       h * 64 + kt * 32 + quad * 8];

  // staging pointers (source-side XOR chunk swizzle); 2 K + 2 V per thread
  const int src_e = (((lane & 3) ^ ((lane >> 3) & 3))) * 8;
  const bf16* gK[2];
  const bf16* gV[2];
#pragma unroll
  for (int t = 0; t < 2; ++t) {
    int o = t * 4096 + w * 1024 + lane * 16;  // byte in 8KB K image
    int cK = o >> 12, rK = (o & 4095) >> 6;
    gK[t] = Kb + (size_t)(kv0 + rK) * DM + h * 64 + cK * 32 + src_e;
    int dV = w * 16 + (lane >> 2);            // V image: [t][dV][32]
    gV[t] = Vtb + (size_t)(h * 64 + dV) * SQ + kv0 + t * 32 + src_e;
  }

  // prologue: stage K(0)+V(0) into buf 0
#pragma unroll
  for (int t = 0; t < 2; ++t) {
    async16(gK[t], (bf16*)(smem + t * 4096 + w * 1024));
    async16(gV[t], (bf16*)(smem + 8192 + t * 4096 + w * 1024));
    gK[t] += 64 * DM;
    gV[t] += 64;
  }

  floatx4 o_acc[4][2] = {};
  float l_s[2] = {0.f, 0.f};
  const int cswz = ((lane >> 4) ^ ((lane >> 1) & 3)) * 8;

  for (int j = 0; j < n_it; ++j) {
    __syncthreads();  // drains (j) tiles staged last iter: full iter of cover
    if (j + 1 < n_it) {
      char* dst = smem + ((j + 1) & 1) * 16384;
#pragma unroll
      for (int t = 0; t < 2; ++t) {
        async16(gK[t], (bf16*)(dst + t * 4096 + w * 1024));
        async16(gV[t], (bf16*)(dst + 8192 + t * 4096 + w * 1024));
        gK[t] += 64 * DM;
        gV[t] += 64;
      }
    }
    const char* cbuf = smem + (j & 1) * 16384;
    const bf16* kbuf = (const bf16*)cbuf;
    const char* vbuf = cbuf + 8192;

    // QK^T: S[32 kv (kh half)][32 q (qh half)]
    floatx4 s[2][2] = {};
    __builtin_amdgcn_s_setprio(1);
#pragma unroll
    for (int kt = 0; kt < 2; ++kt)
#pragma unroll
      for (int mt = 0; mt < 2; ++mt) {
        bf16x8 a = *(const bf16x8*)&kbuf[kt * 2048 + (kh * 32 + mt * 16 + ql) * 32 + cswz];
#pragma unroll
        for (int nt = 0; nt < 2; ++nt)
          s[mt][nt] = __builtin_amdgcn_mfma_f32_16x16x32_bf16(a, qf[nt][kt],
                                                              s[mt][nt], 0, 0, 0);
      }
    __builtin_amdgcn_s_setprio(0);

    // diagonal lives entirely in the last 64-kv iteration (q tile = 64)
    if (diag && j == n_it - 1) {
#pragma unroll
      for (int mt = 0; mt < 2; ++mt)
#pragma unroll
        for (int nt = 0; nt < 2; ++nt) {
          const int qpos = qh * 32 + nt * 16 + ql;
#pragma unroll
          for (int r = 0; r < 4; ++r) {
            int kpos = kh * 32 + mt * 16 + quad * 4 + r;
            if (kpos > qpos) s[mt][nt][r] = -1e30f;
          }
        }
    }

    // fixed-base softmax: exp2 + pack + tree-sum, one pass
    uint2 pp[2][2];
#pragma unroll
    for (int nt = 0; nt < 2; ++nt) {
      float tsum[2];
#pragma unroll
      for (int mt = 0; mt < 2; ++mt) {
        float p0 = __builtin_amdgcn_exp2f(s[mt][nt][0]);
        float p1 = __builtin_amdgcn_exp2f(s[mt][nt][1]);
        float p2 = __builtin_amdgcn_exp2f(s[mt][nt][2]);
        float p3 = __builtin_amdgcn_exp2f(s[mt][nt][3]);
        pp[mt][nt] = make_uint2(pk2(p0, p1), pk2(p2, p3));
        tsum[mt] = (p0 + p1) + (p2 + p3);
      }
      l_s[nt] += tsum[0] + tsum[1];
    }

#if HAVE_MFMA16
    // PV: O^T[d][q] += V^T(kh half) · P^T, B-frags straight from packed regs
    __builtin_amdgcn_s_setprio(1);
#pragma unroll
    for (int mt = 0; mt < 2; ++mt) {
      short4v bfr[2];
#pragma unroll
      for (int nt = 0; nt < 2; ++nt) {
        union { uint2 u; short4v v; } pb;
        pb.u = pp[mt][nt];
        bfr[nt] = pb.v;
      }
      const char* vbase = vbuf + kh * 4096 +
          (((mt * 2 + (quad >> 1)) ^ ((ql >> 1) & 3)) * 16) +
          (quad & 1) * 8;
#pragma unroll
      for (int mtd = 0; mtd < 4; ++mtd) {
        short4v a = *(const short4v*)(vbase + (mtd * 16 + ql) * 64);
#pragma unroll
        for (int nt = 0; nt < 2; ++nt)
          o_acc[mtd][nt] = __builtin_amdgcn_mfma_f32_16x16x16bf16_1k(
              a, bfr[nt], o_acc[mtd][nt], 0, 0, 0);
      }
    }
    __builtin_amdgcn_s_setprio(0);
#else
    // PV via wave-private LDS P^T transpose (one 32-kv group per wave)
    bf16* lp = lPt + w * 1024;  // 2 KB per wave (32 q rows x 64 B)
    {
#pragma unroll
      for (int nt = 0; nt < 2; ++nt) {
        int q32 = nt * 16 + ql;
        int key = (q32 >> 1) & 7;
#pragma unroll
        for (int mtp = 0; mtp < 2; ++mtp) {
          int slot = mtp * 4 + quad;
          *(uint2*)((char*)lp + q32 * 64 + ((slot ^ key) * 8)) = pp[mtp][nt];
        }
      }
      bf16x8 bp[2];
#pragma unroll
      for (int nt = 0; nt < 2; ++nt) {
        int q32 = nt * 16 + ql;
        int key = (q32 >> 1) & 7;
        union { uint2 u[2]; bf16x8 v; } pb;
        pb.u[0] = *(uint2*)((char*)lp + q32 * 64 + (((2 * quad) ^ key) * 8));
        pb.u[1] = *(uint2*)((char*)lp + q32 * 64 + (((2 * quad + 1) ^ key) * 8));
        bp[nt] = pb.v;
      }
      __builtin_amdgcn_s_setprio(1);
#pragma unroll
      for (int mtd = 0; mtd < 4; ++mtd) {
        bf16x8 a = *(const bf16x8*)((const bf16*)vbuf + kh * 2048 +
                                    (mtd * 16 + ql) * 32 + cswz);
#pragma unroll
        for (int nt = 0; nt < 2; ++nt)
          o_acc[mtd][nt] = __builtin_amdgcn_mfma_f32_16x16x32_bf16(
              a, bp[nt], o_acc[mtd][nt], 0, 0, 0);
      }
      __builtin_amdgcn_s_setprio(0);
    }
#endif
  }

  // ---- cross-wave kv-half reduction through the free LDS buffer ----------
  char* fb = smem + ((n_it & 1) * 16384);        // buffer not computed last
  char* lb = smem + (((n_it - 1) & 1) * 16384);  // last-computed buffer
  __syncthreads();  // all PV reads of last buffer done
  if (kh == 1) {
    char* po = fb + (w - 2) * 8192;
#pragma unroll
    for (int nt = 0; nt < 2; ++nt)
#pragma unroll
      for (int mtd = 0; mtd < 4; ++mtd)
        *(floatx4*)(po + (nt * 4 + mtd) * 1024 + lane * 16) = o_acc[mtd][nt];
    float2* pl = (float2*)(lb + (w - 2) * 512);
    pl[lane] = make_float2(l_s[0], l_s[1]);
  }
  __syncthreads();
  if (kh == 0) {
    char* po = fb + w * 8192;
#pragma unroll
    for (int nt = 0; nt < 2; ++nt)
#pragma unroll
      for (int mtd = 0; mtd < 4; ++mtd)
        o_acc[mtd][nt] += *(const floatx4*)(po + (nt * 4 + mtd) * 1024 + lane * 16);
    float2 l2 = ((const float2*)(lb + w * 512))[lane];
    l_s[0] += l2.x;
    l_s[1] += l2.y;

    // finalize l across the 4 lane-groups
    float lf[2];
#pragma unroll
    for (int nt = 0; nt < 2; ++nt) {
      float ls = l_s[nt];
      ls += __shfl_xor(ls, 16);
      ls += __shfl_xor(ls, 32);
      lf[nt] = ls;
    }

    if (qb < 32) {
      // single-chunk tile: normalized direct store
#pragma unroll
      for (int nt = 0; nt < 2; ++nt) {
        float rl = 1.0f / lf[nt];
        int qg = qb * 64 + qh * 32 + nt * 16 + ql;
#pragma unroll
        for (int mtd = 0; mtd < 4; ++mtd) {
          uint32_t lo = pk2(o_acc[mtd][nt][0] * rl, o_acc[mtd][nt][1] * rl);
          uint32_t hi = pk2(o_acc[mtd][nt][2] * rl, o_acc[mtd][nt][3] * rl);
          *(uint2*)&Ob[(size_t)qg * DM + h * 64 + mtd * 16 + quad * 4] =
              make_uint2(lo, hi);
        }
      }
    } else {
      const int ps = (h * 64 + qb) * 2 + c;
#pragma unroll
      for (int nt = 0; nt < 2; ++nt) {
        int q = qh * 32 + nt * 16 + ql;
        if (quad == 0) Lpart[ps * 64 + q] = lf[nt];
#pragma unroll
        for (int mtd = 0; mtd < 4; ++mtd) {
          uint32_t lo = pk2(o_acc[mtd][nt][0], o_acc[mtd][nt][1]);
          uint32_t hi = pk2(o_acc[mtd][nt][2], o_acc[mtd][nt][3]);
          *(uint2*)&OpartB[(size_t)ps * 4096 + q * 64 + mtd * 16 + quad * 4] =
              make_uint2(lo, hi);
        }
      }
    }
  }
}

extern "C" void kernel_launch(void* const* d_in, const int* in_sizes, int n_in,
                              void* d_out, int out_size, void* d_ws,
                              size_t ws_size, hipStream_t stream) {
  const float* x  = (const float*)d_in[0];
  const float* wq = (const float*)d_in[1];
  const float* wk = (const float*)d_in[2];
  const float* wv = (const float*)d_in[3];
  const float* wp = (const float*)d_in[4];
  char* ws = (char*)d_ws;
  // Lpart lives in the xb region (dead after qkv; attn rewrites before
  // proj reads). Peak ws usage = 48771072 B.
  float* Lpart = (float*)(ws);             // 1536*64*4 = 393216 (inside xb)
  bf16* xb   = (bf16*)(ws);
  bf16* wqb  = (bf16*)(ws + 6291456);
  bf16* wkb  = (bf16*)(ws + 7471104);
  bf16* wvb  = (bf16*)(ws + 8650752);
  bf16* wpb  = (bf16*)(ws + 9830400);
  bf16* Qb   = (bf16*)(ws + 11010048);
  bf16* Kb   = (bf16*)(ws + 17301504);
  bf16* Vtb  = (bf16*)(ws + 23592960);
  bf16* Ob   = (bf16*)(ws + 29884416);
  uint16_t* OpartB = (uint16_t*)(ws + 36175872);  // 1536 x 4096 bf16 -> 48771072

  cvt_kernel<<<5376, 256, 0, stream>>>(x, wq, wk, wv, wp, xb, wqb, wkb, wvb, wpb);
  qkv_kernel<<<dim3(32, 6, 3), 256, 0, stream>>>(xb, wqb, wkb, wvb, Qb, Kb, Vtb);
  attn_kernel<<<1152, 256, 0, stream>>>(Qb, Kb, Vtb, OpartB, Lpart, Ob);
  proj_kernel<<<dim3(64, 6), 256, 0, stream>>>(Ob, wpb, OpartB, Lpart,
                                               (float*)d_out);
}